// Round 1
// baseline (10059.219 us; speedup 1.0000x reference)
//
#include <hip/hip_runtime.h>
#include <cmath>

#define NV   262144
#define NE   786432
#define CIMG 256
#define HID  128
#define NPIX 4096
#define DIN  131
#define KPAD 132
#define LROWS 124   // W rows staged in LDS (124*128*4 = 62KB); rows 124..130 in regs

__device__ __forceinline__ void fma4(float4& a, float s, const float4& w) {
    a.x += s * w.x; a.y += s * w.y; a.z += s * w.z; a.w += s * w.w;
}

// P[p][j] = sum_c img[c][p] * bw[c][j]   (bilinear commutes with channel matmul)
__global__ __launch_bounds__(256) void k_project(const float* __restrict__ img,
                                                 const float* __restrict__ bw,
                                                 float* __restrict__ P) {
    int j  = threadIdx.x & (HID - 1);
    int pr = threadIdx.x >> 7;          // 0..1
    int pbase = blockIdx.x * 32;
    float acc[16];
#pragma unroll
    for (int i = 0; i < 16; ++i) acc[i] = 0.f;
    for (int c = 0; c < CIMG; ++c) {
        float bwv = bw[c * HID + j];
        const float* ip = img + (size_t)c * NPIX + pbase + pr;
#pragma unroll
        for (int i = 0; i < 16; ++i) acc[i] += ip[2 * i] * bwv;
    }
#pragma unroll
    for (int i = 0; i < 16; ++i) P[(size_t)(pbase + 2 * i + pr) * HID + j] = acc[i];
}

// feats[v][0..127] = relu(bilerp(P, verts.xy) + bb); feats[v][128..130] = verts; [131]=0
__global__ __launch_bounds__(256) void k_sample(const float* __restrict__ P,
                                                const float* __restrict__ verts,
                                                const float* __restrict__ bb,
                                                float* __restrict__ feats) {
    int c = threadIdx.x & (HID - 1);
    int v = blockIdx.x * 2 + (threadIdx.x >> 7);
    float vx = verts[(size_t)v * 3 + 0];
    float vy = verts[(size_t)v * 3 + 1];
    float px = (vx + 1.f) * 31.5f;
    float py = (vy + 1.f) * 31.5f;
    float x0f = floorf(px), y0f = floorf(py);
    float wx = px - x0f,   wy = py - y0f;
    int x0 = (int)x0f, y0 = (int)y0f;
    int x0i = min(max(x0, 0), 63);
    int x1i = min(x0i + 1, 63);
    int y0i = min(max(y0, 0), 63);
    int y1i = min(y0i + 1, 63);
    const float* p00 = P + (size_t)(y0i * 64 + x0i) * HID;
    const float* p01 = P + (size_t)(y0i * 64 + x1i) * HID;
    const float* p10 = P + (size_t)(y1i * 64 + x0i) * HID;
    const float* p11 = P + (size_t)(y1i * 64 + x1i) * HID;
    float v00 = p00[c], v01 = p01[c], v10 = p10[c], v11 = p11[c];
    float top = v00 * (1.f - wx) + v01 * wx;
    float bot = v10 * (1.f - wx) + v11 * wx;
    float h = top * (1.f - wy) + bot * wy + bb[c];
    h = fmaxf(h, 0.f);
    float* fr = feats + (size_t)v * KPAD;
    fr[c] = h;
    if (c < 3)  fr[HID + c] = verts[(size_t)v * 3 + c];
    if (c == 3) fr[HID + 3] = 0.f;
}

// out[v][0..127] = feats[v][0..130] @ W + bias   (fp32, W rows 0..123 in LDS)
__global__ __launch_bounds__(256) void k_gemm(const float* __restrict__ feats,
                                              const float* __restrict__ W,
                                              const float* __restrict__ bias,
                                              float* __restrict__ outp) {
    __shared__ float wl[LROWS * HID];           // 62 KB -> 2 blocks/CU
    for (int idx = threadIdx.x; idx < LROWS * HID; idx += 256) wl[idx] = W[idx];
    __syncthreads();
    int cq = threadIdx.x & 31;                  // 4 channels: 4*cq..4*cq+3
    int vr = threadIdx.x >> 5;                  // 0..7
    float4 tw[7];                               // W rows 124..130
#pragma unroll
    for (int t = 0; t < 7; ++t)
        tw[t] = *(const float4*)&W[(size_t)(LROWS + t) * HID + 4 * cq];
    float4 bv = *(const float4*)&bias[4 * cq];

    for (int it = 0; it < 8; ++it) {
        int vbase = blockIdx.x * 256 + it * 32 + vr;   // this thread: vbase + 8*i
        float4 acc[4];
#pragma unroll
        for (int i = 0; i < 4; ++i) acc[i] = bv;
#pragma unroll 2
        for (int kk = 0; kk < LROWS; kk += 4) {
            float4 f[4];
#pragma unroll
            for (int i = 0; i < 4; ++i)
                f[i] = *(const float4*)(feats + (size_t)(vbase + 8 * i) * KPAD + kk);
#pragma unroll
            for (int j = 0; j < 4; ++j) {
                float4 wv = *(const float4*)&wl[(kk + j) * HID + 4 * cq];
#pragma unroll
                for (int i = 0; i < 4; ++i)
                    fma4(acc[i], ((const float*)&f[i])[j], wv);
            }
        }
#pragma unroll
        for (int i = 0; i < 4; ++i) {
            const float* fr = feats + (size_t)(vbase + 8 * i) * KPAD;
            float4 fA = *(const float4*)(fr + LROWS);   // rows 124..127
            float4 fB = *(const float4*)(fr + 128);     // rows 128..130 (+pad)
            fma4(acc[i], fA.x, tw[0]); fma4(acc[i], fA.y, tw[1]);
            fma4(acc[i], fA.z, tw[2]); fma4(acc[i], fA.w, tw[3]);
            fma4(acc[i], fB.x, tw[4]); fma4(acc[i], fB.y, tw[5]);
            fma4(acc[i], fB.z, tw[6]);
            *(float4*)(outp + (size_t)(vbase + 8 * i) * HID + 4 * cq) = acc[i];
        }
    }
}

// acc[e0] += z[e1]; acc[e1] += z[e0]  (thread = one edge x 4 channels)
__global__ __launch_bounds__(256) void k_scatter(const int* __restrict__ edges,
                                                 const float* __restrict__ z,
                                                 float* __restrict__ acc) {
    int idx = blockIdx.x * 256 + threadIdx.x;
    int e  = idx >> 5;
    int cq = idx & 31;
    int e0 = edges[2 * e];
    int e1 = edges[2 * e + 1];
    float4 za = *(const float4*)&z[(size_t)e1 * HID + 4 * cq];
    float* a0 = acc + (size_t)e0 * HID + 4 * cq;
    unsafeAtomicAdd(a0 + 0, za.x);
    unsafeAtomicAdd(a0 + 1, za.y);
    unsafeAtomicAdd(a0 + 2, za.z);
    unsafeAtomicAdd(a0 + 3, za.w);
    float4 zb = *(const float4*)&z[(size_t)e0 * HID + 4 * cq];
    float* a1 = acc + (size_t)e1 * HID + 4 * cq;
    unsafeAtomicAdd(a1 + 0, zb.x);
    unsafeAtomicAdd(a1 + 1, zb.y);
    unsafeAtomicAdd(a1 + 2, zb.z);
    unsafeAtomicAdd(a1 + 3, zb.w);
}

__global__ __launch_bounds__(256) void k_relu_to_feats(const float* __restrict__ acc,
                                                       float* __restrict__ feats) {
    int idx = blockIdx.x * 256 + threadIdx.x;   // over NV*32 float4s
    int v  = idx >> 5;
    int cq = idx & 31;
    float4 a = ((const float4*)acc)[idx];
    a.x = fmaxf(a.x, 0.f); a.y = fmaxf(a.y, 0.f);
    a.z = fmaxf(a.z, 0.f); a.w = fmaxf(a.w, 0.f);
    *(float4*)(feats + (size_t)v * KPAD + 4 * cq) = a;
}

__global__ __launch_bounds__(256) void k_relu_inplace(float* __restrict__ acc) {
    int idx = blockIdx.x * 256 + threadIdx.x;
    float4 a = ((const float4*)acc)[idx];
    a.x = fmaxf(a.x, 0.f); a.y = fmaxf(a.y, 0.f);
    a.z = fmaxf(a.z, 0.f); a.w = fmaxf(a.w, 0.f);
    ((float4*)acc)[idx] = a;
}

// new_verts = verts + tanh(concat(fin, verts) @ ow + ob)
__global__ __launch_bounds__(256) void k_offset(const float* __restrict__ fin,
                                                const float* __restrict__ verts,
                                                const float* __restrict__ ow,
                                                const float* __restrict__ ob,
                                                float* __restrict__ outp) {
    __shared__ float owl[DIN * 3];
    for (int idx = threadIdx.x; idx < DIN * 3; idx += 256) owl[idx] = ow[idx];
    __syncthreads();
    int v = blockIdx.x * 256 + threadIdx.x;
    const float* f = fin + (size_t)v * HID;
    float d0 = ob[0], d1 = ob[1], d2 = ob[2];
#pragma unroll 8
    for (int q = 0; q < 32; ++q) {
        float4 fl = ((const float4*)f)[q];
#pragma unroll
        for (int j = 0; j < 4; ++j) {
            float fv = ((const float*)&fl)[j];
            int k = 4 * q + j;
            d0 += fv * owl[k * 3 + 0];
            d1 += fv * owl[k * 3 + 1];
            d2 += fv * owl[k * 3 + 2];
        }
    }
    float vx = verts[(size_t)v * 3 + 0];
    float vy = verts[(size_t)v * 3 + 1];
    float vz = verts[(size_t)v * 3 + 2];
    d0 += vx * owl[128 * 3 + 0] + vy * owl[129 * 3 + 0] + vz * owl[130 * 3 + 0];
    d1 += vx * owl[128 * 3 + 1] + vy * owl[129 * 3 + 1] + vz * owl[130 * 3 + 1];
    d2 += vx * owl[128 * 3 + 2] + vy * owl[129 * 3 + 2] + vz * owl[130 * 3 + 2];
    outp[(size_t)v * 3 + 0] = vx + tanhf(d0);
    outp[(size_t)v * 3 + 1] = vy + tanhf(d1);
    outp[(size_t)v * 3 + 2] = vz + tanhf(d2);
}

extern "C" void kernel_launch(void* const* d_in, const int* in_sizes, int n_in,
                              void* d_out, int out_size, void* d_ws, size_t ws_size,
                              hipStream_t stream) {
    const float* x     = (const float*)d_in[0];
    const float* verts = (const float*)d_in[1];
    const int*   edges = (const int*)d_in[2];
    const float* bw    = (const float*)d_in[3];
    const float* bb    = (const float*)d_in[4];
    const float* w0    = (const float*)d_in[5];
    const float* b0    = (const float*)d_in[6];
    const float* w1    = (const float*)d_in[7];
    const float* b1    = (const float*)d_in[8];
    const float* ow    = (const float*)d_in[9];
    const float* ob    = (const float*)d_in[10];
    float* out = (float*)d_out;

    float* P     = (float*)d_ws;
    float* feats = P + (size_t)NPIX * HID;
    float* z     = feats + (size_t)NV * KPAD;
    float* acc   = out + (size_t)3 * NV;   // y-accumulator == final vert_feats_nopos slot

    k_project<<<NPIX / 32, 256, 0, stream>>>(x, bw, P);
    k_sample<<<NV / 2, 256, 0, stream>>>(P, verts, bb, feats);

    for (int i = 0; i < 3; ++i) {
        const float* w0i = w0 + (size_t)i * DIN * HID;
        const float* w1i = w1 + (size_t)i * DIN * HID;
        // z = feats @ w1 + b1
        k_gemm<<<NV / 256, 256, 0, stream>>>(feats, w1i, b1 + (size_t)i * HID, z);
        // acc = y = feats @ w0 + b0
        k_gemm<<<NV / 256, 256, 0, stream>>>(feats, w0i, b0 + (size_t)i * HID, acc);
        // acc += scatter of z over edges
        k_scatter<<<(NE * 32) / 256, 256, 0, stream>>>(edges, z, acc);
        // feats = relu(acc) (last layer: in place, becomes output)
        if (i < 2) k_relu_to_feats<<<(NV * 32) / 256, 256, 0, stream>>>(acc, feats);
        else       k_relu_inplace<<<(NV * 32) / 256, 256, 0, stream>>>(acc);
    }
    k_offset<<<NV / 256, 256, 0, stream>>>(acc, verts, ow, ob, out);
}

// Round 2
// 2485.111 us; speedup vs baseline: 4.0478x; 4.0478x over previous
//
#include <hip/hip_runtime.h>
#include <hip/hip_bf16.h>
#include <cmath>

#define NV   262144
#define NE   786432
#define CIMG 256
#define HID  128
#define NPIX 4096
#define DIN  131
#define KPAD 132
#define LROWS 124   // W rows staged in LDS (124*128*4 = 62KB); rows 124..130 in regs

__device__ __forceinline__ void fma4(float4& a, float s, const float4& w) {
    a.x += s * w.x; a.y += s * w.y; a.z += s * w.z; a.w += s * w.w;
}

__device__ __forceinline__ unsigned short f2bf(float v) {
    unsigned int u = __float_as_uint(v);
    u = u + 0x7fffu + ((u >> 16) & 1u);   // RNE
    return (unsigned short)(u >> 16);
}
__device__ __forceinline__ float bf2f(unsigned short b) {
    return __uint_as_float(((unsigned int)b) << 16);
}

// P[p][j] = sum_c img[c][p] * bw[c][j]   (bilinear commutes with channel matmul)
__global__ __launch_bounds__(256) void k_project(const float* __restrict__ img,
                                                 const float* __restrict__ bw,
                                                 float* __restrict__ P) {
    int j  = threadIdx.x & (HID - 1);
    int pr = threadIdx.x >> 7;          // 0..1
    int pbase = blockIdx.x * 32;
    float acc[16];
#pragma unroll
    for (int i = 0; i < 16; ++i) acc[i] = 0.f;
    for (int c = 0; c < CIMG; ++c) {
        float bwv = bw[c * HID + j];
        const float* ip = img + (size_t)c * NPIX + pbase + pr;
#pragma unroll
        for (int i = 0; i < 16; ++i) acc[i] += ip[2 * i] * bwv;
    }
#pragma unroll
    for (int i = 0; i < 16; ++i) P[(size_t)(pbase + 2 * i + pr) * HID + j] = acc[i];
}

// feats[v][0..127] = relu(bilerp(P, verts.xy) + bb); feats[v][128..130] = verts; [131]=0
__global__ __launch_bounds__(256) void k_sample(const float* __restrict__ P,
                                                const float* __restrict__ verts,
                                                const float* __restrict__ bb,
                                                float* __restrict__ feats) {
    int c = threadIdx.x & (HID - 1);
    int v = blockIdx.x * 2 + (threadIdx.x >> 7);
    float vx = verts[(size_t)v * 3 + 0];
    float vy = verts[(size_t)v * 3 + 1];
    float px = (vx + 1.f) * 31.5f;
    float py = (vy + 1.f) * 31.5f;
    float x0f = floorf(px), y0f = floorf(py);
    float wx = px - x0f,   wy = py - y0f;
    int x0 = (int)x0f, y0 = (int)y0f;
    int x0i = min(max(x0, 0), 63);
    int x1i = min(x0i + 1, 63);
    int y0i = min(max(y0, 0), 63);
    int y1i = min(y0i + 1, 63);
    const float* p00 = P + (size_t)(y0i * 64 + x0i) * HID;
    const float* p01 = P + (size_t)(y0i * 64 + x1i) * HID;
    const float* p10 = P + (size_t)(y1i * 64 + x0i) * HID;
    const float* p11 = P + (size_t)(y1i * 64 + x1i) * HID;
    float v00 = p00[c], v01 = p01[c], v10 = p10[c], v11 = p11[c];
    float top = v00 * (1.f - wx) + v01 * wx;
    float bot = v10 * (1.f - wx) + v11 * wx;
    float h = top * (1.f - wy) + bot * wy + bb[c];
    h = fmaxf(h, 0.f);
    float* fr = feats + (size_t)v * KPAD;
    fr[c] = h;
    if (c < 3)  fr[HID + c] = verts[(size_t)v * 3 + c];
    if (c == 3) fr[HID + 3] = 0.f;
}

// out[v][0..127] = feats[v][0..130] @ W + bias. BF16OUT: store bf16 (for z).
template <bool BF16OUT>
__global__ __launch_bounds__(256) void k_gemm(const float* __restrict__ feats,
                                              const float* __restrict__ W,
                                              const float* __restrict__ bias,
                                              void* __restrict__ outp) {
    __shared__ float wl[LROWS * HID];           // 62 KB -> 2 blocks/CU
    for (int idx = threadIdx.x; idx < LROWS * HID; idx += 256) wl[idx] = W[idx];
    __syncthreads();
    int cq = threadIdx.x & 31;                  // 4 channels: 4*cq..4*cq+3
    int vr = threadIdx.x >> 5;                  // 0..7
    float4 tw[7];                               // W rows 124..130
#pragma unroll
    for (int t = 0; t < 7; ++t)
        tw[t] = *(const float4*)&W[(size_t)(LROWS + t) * HID + 4 * cq];
    float4 bv = *(const float4*)&bias[4 * cq];

    for (int it = 0; it < 8; ++it) {
        int vbase = blockIdx.x * 256 + it * 32 + vr;   // this thread: vbase + 8*i
        float4 acc[4];
#pragma unroll
        for (int i = 0; i < 4; ++i) acc[i] = bv;
#pragma unroll 2
        for (int kk = 0; kk < LROWS; kk += 4) {
            float4 f[4];
#pragma unroll
            for (int i = 0; i < 4; ++i)
                f[i] = *(const float4*)(feats + (size_t)(vbase + 8 * i) * KPAD + kk);
#pragma unroll
            for (int j = 0; j < 4; ++j) {
                float4 wv = *(const float4*)&wl[(kk + j) * HID + 4 * cq];
#pragma unroll
                for (int i = 0; i < 4; ++i)
                    fma4(acc[i], ((const float*)&f[i])[j], wv);
            }
        }
#pragma unroll
        for (int i = 0; i < 4; ++i) {
            const float* fr = feats + (size_t)(vbase + 8 * i) * KPAD;
            float4 fA = *(const float4*)(fr + LROWS);   // rows 124..127
            float4 fB = *(const float4*)(fr + 128);     // rows 128..130 (+pad)
            fma4(acc[i], fA.x, tw[0]); fma4(acc[i], fA.y, tw[1]);
            fma4(acc[i], fA.z, tw[2]); fma4(acc[i], fA.w, tw[3]);
            fma4(acc[i], fB.x, tw[4]); fma4(acc[i], fB.y, tw[5]);
            fma4(acc[i], fB.z, tw[6]);
            if (BF16OUT) {
                ushort4 o;
                o.x = f2bf(acc[i].x); o.y = f2bf(acc[i].y);
                o.z = f2bf(acc[i].z); o.w = f2bf(acc[i].w);
                *(ushort4*)((unsigned short*)outp + (size_t)(vbase + 8 * i) * HID + 4 * cq) = o;
            } else {
                *(float4*)((float*)outp + (size_t)(vbase + 8 * i) * HID + 4 * cq) = acc[i];
            }
        }
    }
}

// ---- CSR build ----
__global__ __launch_bounds__(256) void k_degree(const int* __restrict__ edges,
                                                int* __restrict__ rowstart) {
    int e = blockIdx.x * 256 + threadIdx.x;
    int e0 = edges[2 * e], e1 = edges[2 * e + 1];
    atomicAdd(&rowstart[1 + e0], 1);
    atomicAdd(&rowstart[1 + e1], 1);
}

// block sums of 1024-element chunks of rowstart[0..NV]
__global__ __launch_bounds__(256) void k_scan1(const int* __restrict__ rowstart,
                                               int* __restrict__ bsum) {
    __shared__ int s[256];
    int base = blockIdx.x * 1024 + threadIdx.x * 4;
    int t = 0;
#pragma unroll
    for (int j = 0; j < 4; ++j) { int idx = base + j; if (idx <= NV) t += rowstart[idx]; }
    s[threadIdx.x] = t;
    __syncthreads();
    for (int off = 1; off < 256; off <<= 1) {
        int v = (threadIdx.x >= off) ? s[threadIdx.x - off] : 0;
        __syncthreads();
        s[threadIdx.x] += v;
        __syncthreads();
    }
    if (threadIdx.x == 255) bsum[blockIdx.x] = s[255];
}

// exclusive scan of bsum[0..256] (257 entries) -> boff
__global__ __launch_bounds__(512) void k_scan2(const int* __restrict__ bsum,
                                               int* __restrict__ boff) {
    __shared__ int s[512];
    int i = threadIdx.x;
    s[i] = (i < 257) ? bsum[i] : 0;
    __syncthreads();
    for (int off = 1; off < 512; off <<= 1) {
        int v = (i >= off) ? s[i - off] : 0;
        __syncthreads();
        s[i] += v;
        __syncthreads();
    }
    if (i < 257) boff[i] = (i == 0) ? 0 : s[i - 1] - bsum[i] + ((i < 257) ? 0 : 0);
    // exclusive: sum of elements before i = inclusive(i) - bsum[i]
    if (i < 257) boff[i] = s[i] - bsum[i];
}

// in-place inclusive scan of each 1024-chunk + boff; also write cursor[v]=rowstart[v]
__global__ __launch_bounds__(256) void k_scan3(int* __restrict__ rowstart,
                                               const int* __restrict__ boff,
                                               int* __restrict__ cursor) {
    __shared__ int s[256];
    int base = blockIdx.x * 1024 + threadIdx.x * 4;
    int v[4];
    int t = 0;
#pragma unroll
    for (int j = 0; j < 4; ++j) {
        int idx = base + j;
        v[j] = (idx <= NV) ? rowstart[idx] : 0;
        t += v[j];
    }
    s[threadIdx.x] = t;
    __syncthreads();
    for (int off = 1; off < 256; off <<= 1) {
        int x = (threadIdx.x >= off) ? s[threadIdx.x - off] : 0;
        __syncthreads();
        s[threadIdx.x] += x;
        __syncthreads();
    }
    int pre = s[threadIdx.x] - t + boff[blockIdx.x];   // exclusive prefix for this thread
    int run = pre;
#pragma unroll
    for (int j = 0; j < 4; ++j) {
        int idx = base + j;
        run += v[j];
        if (idx <= NV) {
            rowstart[idx] = run;
            if (idx < NV) cursor[idx] = run;   // == exclusive offset of vertex idx? no:
        }
    }
}

// fix: cursor must hold the EXCLUSIVE offset (rowstart[v] before neighbors are placed).
// k_scan3 wrote inclusive values; derive cursor separately:
__global__ __launch_bounds__(256) void k_cursor(const int* __restrict__ rowstart,
                                                int* __restrict__ cursor) {
    int v = blockIdx.x * 256 + threadIdx.x;
    cursor[v] = rowstart[v];
}

__global__ __launch_bounds__(256) void k_fill(const int* __restrict__ edges,
                                              int* __restrict__ cursor,
                                              int* __restrict__ adj) {
    int e = blockIdx.x * 256 + threadIdx.x;
    int e0 = edges[2 * e], e1 = edges[2 * e + 1];
    int p0 = atomicAdd(&cursor[e0], 1);
    adj[p0] = e1;
    int p1 = atomicAdd(&cursor[e1], 1);
    adj[p1] = e0;
}

// dest[v][c] = relu(y[v][c] + sum_{u in N(v)} z[u][c]); 32 threads/vertex
__global__ __launch_bounds__(256) void k_gather(const int* __restrict__ rowstart,
                                                const int* __restrict__ adj,
                                                const unsigned short* __restrict__ zbf,
                                                const float* __restrict__ y,
                                                float* __restrict__ dest,
                                                int dstride) {
    int v  = blockIdx.x * 8 + (threadIdx.x >> 5);
    int cq = threadIdx.x & 31;
    int start = rowstart[v], end = rowstart[v + 1];
    float4 a = *(const float4*)(y + (size_t)v * HID + 4 * cq);
    for (int n = start; n < end; ++n) {
        int u = adj[n];
        ushort4 zz = *(const ushort4*)(zbf + (size_t)u * HID + 4 * cq);
        a.x += bf2f(zz.x); a.y += bf2f(zz.y);
        a.z += bf2f(zz.z); a.w += bf2f(zz.w);
    }
    a.x = fmaxf(a.x, 0.f); a.y = fmaxf(a.y, 0.f);
    a.z = fmaxf(a.z, 0.f); a.w = fmaxf(a.w, 0.f);
    *(float4*)(dest + (size_t)v * dstride + 4 * cq) = a;
}

// new_verts = verts + tanh(concat(fin, verts) @ ow + ob)
__global__ __launch_bounds__(256) void k_offset(const float* __restrict__ fin,
                                                const float* __restrict__ verts,
                                                const float* __restrict__ ow,
                                                const float* __restrict__ ob,
                                                float* __restrict__ outp) {
    __shared__ float owl[DIN * 3];
    for (int idx = threadIdx.x; idx < DIN * 3; idx += 256) owl[idx] = ow[idx];
    __syncthreads();
    int v = blockIdx.x * 256 + threadIdx.x;
    const float* f = fin + (size_t)v * HID;
    float d0 = ob[0], d1 = ob[1], d2 = ob[2];
#pragma unroll 8
    for (int q = 0; q < 32; ++q) {
        float4 fl = ((const float4*)f)[q];
#pragma unroll
        for (int j = 0; j < 4; ++j) {
            float fv = ((const float*)&fl)[j];
            int k = 4 * q + j;
            d0 += fv * owl[k * 3 + 0];
            d1 += fv * owl[k * 3 + 1];
            d2 += fv * owl[k * 3 + 2];
        }
    }
    float vx = verts[(size_t)v * 3 + 0];
    float vy = verts[(size_t)v * 3 + 1];
    float vz = verts[(size_t)v * 3 + 2];
    d0 += vx * owl[128 * 3 + 0] + vy * owl[129 * 3 + 0] + vz * owl[130 * 3 + 0];
    d1 += vx * owl[128 * 3 + 1] + vy * owl[129 * 3 + 1] + vz * owl[130 * 3 + 1];
    d2 += vx * owl[128 * 3 + 2] + vy * owl[129 * 3 + 2] + vz * owl[130 * 3 + 2];
    outp[(size_t)v * 3 + 0] = vx + tanhf(d0);
    outp[(size_t)v * 3 + 1] = vy + tanhf(d1);
    outp[(size_t)v * 3 + 2] = vz + tanhf(d2);
}

extern "C" void kernel_launch(void* const* d_in, const int* in_sizes, int n_in,
                              void* d_out, int out_size, void* d_ws, size_t ws_size,
                              hipStream_t stream) {
    const float* x     = (const float*)d_in[0];
    const float* verts = (const float*)d_in[1];
    const int*   edges = (const int*)d_in[2];
    const float* bw    = (const float*)d_in[3];
    const float* bb    = (const float*)d_in[4];
    const float* w0    = (const float*)d_in[5];
    const float* b0    = (const float*)d_in[6];
    const float* w1    = (const float*)d_in[7];
    const float* b1    = (const float*)d_in[8];
    const float* ow    = (const float*)d_in[9];
    const float* ob    = (const float*)d_in[10];
    float* out = (float*)d_out;

    char* w = (char*)d_ws;
    float* P            = (float*)w;                 w += (size_t)NPIX * HID * 4;
    float* feats        = (float*)w;                 w += (size_t)NV * KPAD * 4;
    unsigned short* zbf = (unsigned short*)w;        w += (size_t)NV * HID * 2;
    int* adj            = (int*)w;                   w += (size_t)2 * NE * 4;
    int* rowstart       = (int*)w;                   w += (size_t)(NV + 1) * 4;
    int* cursor         = (int*)w;                   w += (size_t)NV * 4;
    int* bsum           = (int*)w;                   w += 512 * 4;
    int* boff           = (int*)w;                   w += 512 * 4;
    float* acc          = out + (size_t)3 * NV;      // y accumulator == final feats slot

    // ---- CSR build (once; reused all 3 layers) ----
    hipMemsetAsync(rowstart, 0, (size_t)(NV + 1) * 4, stream);
    k_degree<<<NE / 256, 256, 0, stream>>>(edges, rowstart);
    k_scan1<<<257, 256, 0, stream>>>(rowstart, bsum);
    k_scan2<<<1, 512, 0, stream>>>(bsum, boff);
    k_scan3<<<257, 256, 0, stream>>>(rowstart, boff, cursor);
    k_cursor<<<NV / 256, 256, 0, stream>>>(rowstart, cursor);
    k_fill<<<NE / 256, 256, 0, stream>>>(edges, cursor, adj);

    k_project<<<NPIX / 32, 256, 0, stream>>>(x, bw, P);
    k_sample<<<NV / 2, 256, 0, stream>>>(P, verts, bb, feats);

    for (int i = 0; i < 3; ++i) {
        const float* w0i = w0 + (size_t)i * DIN * HID;
        const float* w1i = w1 + (size_t)i * DIN * HID;
        k_gemm<true ><<<NV / 256, 256, 0, stream>>>(feats, w1i, b1 + (size_t)i * HID, zbf);
        k_gemm<false><<<NV / 256, 256, 0, stream>>>(feats, w0i, b0 + (size_t)i * HID, acc);
        if (i < 2) k_gather<<<NV / 8, 256, 0, stream>>>(rowstart, adj, zbf, acc, feats, KPAD);
        else       k_gather<<<NV / 8, 256, 0, stream>>>(rowstart, adj, zbf, acc, acc, HID);
    }
    k_offset<<<NV / 256, 256, 0, stream>>>(acc, verts, ow, ob, out);
}

// Round 3
// 1243.416 us; speedup vs baseline: 8.0900x; 1.9986x over previous
//
#include <hip/hip_runtime.h>
#include <cmath>

#define NV   262144
#define NE   786432
#define CIMG 256
#define HID  128
#define NPIX 4096
#define DIN  131
#define KB   160    // bf16 feats padded K (131 -> 160, zeros)

typedef short bf8v __attribute__((ext_vector_type(8)));
typedef float f4v  __attribute__((ext_vector_type(4)));

__device__ __forceinline__ unsigned short f2bf(float v) {
    unsigned int u = __float_as_uint(v);
    u = u + 0x7fffu + ((u >> 16) & 1u);   // RNE
    return (unsigned short)(u >> 16);
}
__device__ __forceinline__ float bf2f(unsigned short b) {
    return __uint_as_float(((unsigned int)b) << 16);
}

// P[p][j] = sum_c img[c][p] * bw[c][j]   (bilinear commutes with channel matmul)
__global__ __launch_bounds__(256) void k_project(const float* __restrict__ img,
                                                 const float* __restrict__ bw,
                                                 float* __restrict__ P) {
    int j  = threadIdx.x & (HID - 1);
    int pr = threadIdx.x >> 7;
    int pbase = blockIdx.x * 32;
    float acc[16];
#pragma unroll
    for (int i = 0; i < 16; ++i) acc[i] = 0.f;
    for (int c = 0; c < CIMG; ++c) {
        float bwv = bw[c * HID + j];
        const float* ip = img + (size_t)c * NPIX + pbase + pr;
#pragma unroll
        for (int i = 0; i < 16; ++i) acc[i] += ip[2 * i] * bwv;
    }
#pragma unroll
    for (int i = 0; i < 16; ++i) P[(size_t)(pbase + 2 * i + pr) * HID + j] = acc[i];
}

// feats[v][0..127] = relu(bilerp + bb) bf16; [128..130]=verts; [131..159]=0
__global__ __launch_bounds__(256) void k_sample(const float* __restrict__ P,
                                                const float* __restrict__ verts,
                                                const float* __restrict__ bb,
                                                unsigned short* __restrict__ feats) {
    int c = threadIdx.x & (HID - 1);
    int v = blockIdx.x * 2 + (threadIdx.x >> 7);
    float vx = verts[(size_t)v * 3 + 0];
    float vy = verts[(size_t)v * 3 + 1];
    float px = (vx + 1.f) * 31.5f;
    float py = (vy + 1.f) * 31.5f;
    float x0f = floorf(px), y0f = floorf(py);
    float wx = px - x0f,   wy = py - y0f;
    int x0 = (int)x0f, y0 = (int)y0f;
    int x0i = min(max(x0, 0), 63);
    int x1i = min(x0i + 1, 63);
    int y0i = min(max(y0, 0), 63);
    int y1i = min(y0i + 1, 63);
    const float* p00 = P + (size_t)(y0i * 64 + x0i) * HID;
    const float* p01 = P + (size_t)(y0i * 64 + x1i) * HID;
    const float* p10 = P + (size_t)(y1i * 64 + x0i) * HID;
    const float* p11 = P + (size_t)(y1i * 64 + x1i) * HID;
    float v00 = p00[c], v01 = p01[c], v10 = p10[c], v11 = p11[c];
    float top = v00 * (1.f - wx) + v01 * wx;
    float bot = v10 * (1.f - wx) + v11 * wx;
    float h = fmaxf(top * (1.f - wy) + bot * wy + bb[c], 0.f);
    unsigned short* fr = feats + (size_t)v * KB;
    fr[c] = f2bf(h);
    if (c < 32) {
        float val = (c < 3) ? verts[(size_t)v * 3 + c] : 0.f;
        fr[128 + c] = f2bf(val);
    }
}

// Wt[m][n][k] bf16, m = layer*2+g, transposed from W[k][n], zero-padded k>=131
__global__ __launch_bounds__(256) void k_prepw(const float* __restrict__ w0,
                                               const float* __restrict__ w1,
                                               unsigned short* __restrict__ Wt) {
    int idx = blockIdx.x * 256 + threadIdx.x;
    if (idx >= 6 * 128) return;
    int m = idx >> 7;
    int n = idx & 127;
    int layer = m >> 1, g = m & 1;
    const float* W = (g ? w1 : w0) + (size_t)layer * DIN * HID;
    unsigned short* dst = Wt + (size_t)(m * 128 + n) * KB;
    for (int k = 0; k < KB; ++k) {
        float v = (k < DIN) ? W[(size_t)k * HID + n] : 0.f;
        dst[k] = f2bf(v);
    }
}

// Fused MFMA GEMM: y = feats@W0+b0 (bf16), z = feats@W1+b1 (bf16).
// Block = 4 waves; wave w handles cols [32w, 32w+32). B frags in registers.
__global__ __launch_bounds__(256, 2) void k_gemm2(const unsigned short* __restrict__ feats,
                                                  const unsigned short* __restrict__ Wt0,
                                                  const unsigned short* __restrict__ Wt1,
                                                  const float* __restrict__ bias0,
                                                  const float* __restrict__ bias1,
                                                  unsigned short* __restrict__ y,
                                                  unsigned short* __restrict__ z) {
    int lane = threadIdx.x & 63;
    int wave = threadIdx.x >> 6;     // column quarter: cols 32*wave..+31
    int l15  = lane & 15;
    int quad = lane >> 4;

    bf8v bfrag[2][2][5];
#pragma unroll
    for (int g = 0; g < 2; ++g) {
        const unsigned short* Wg = g ? Wt1 : Wt0;
#pragma unroll
        for (int ct = 0; ct < 2; ++ct) {
            int n = wave * 32 + ct * 16 + l15;
#pragma unroll
            for (int ks = 0; ks < 5; ++ks)
                bfrag[g][ct][ks] = *(const bf8v*)(Wg + (size_t)n * KB + ks * 32 + quad * 8);
        }
    }
    float bv[2][2];
#pragma unroll
    for (int g = 0; g < 2; ++g)
#pragma unroll
        for (int ct = 0; ct < 2; ++ct)
            bv[g][ct] = (g ? bias1 : bias0)[wave * 32 + ct * 16 + l15];

    int vb0 = blockIdx.x * 256;
    bf8v a_cur[5], a_nxt[5];
    {
        const unsigned short* ap = feats + (size_t)(vb0 + l15) * KB + quad * 8;
#pragma unroll
        for (int ks = 0; ks < 5; ++ks) a_cur[ks] = *(const bf8v*)(ap + ks * 32);
    }

    for (int it = 0; it < 16; ++it) {
        if (it < 15) {
            const unsigned short* ap = feats + (size_t)(vb0 + (it + 1) * 16 + l15) * KB + quad * 8;
#pragma unroll
            for (int ks = 0; ks < 5; ++ks) a_nxt[ks] = *(const bf8v*)(ap + ks * 32);
        }
        f4v acc[2][2];
#pragma unroll
        for (int g = 0; g < 2; ++g)
#pragma unroll
            for (int ct = 0; ct < 2; ++ct) {
                f4v t = {bv[g][ct], bv[g][ct], bv[g][ct], bv[g][ct]};
                acc[g][ct] = t;
            }
#pragma unroll
        for (int ks = 0; ks < 5; ++ks)
#pragma unroll
            for (int g = 0; g < 2; ++g)
#pragma unroll
                for (int ct = 0; ct < 2; ++ct)
                    acc[g][ct] = __builtin_amdgcn_mfma_f32_16x16x32_bf16(
                        a_cur[ks], bfrag[g][ct][ks], acc[g][ct], 0, 0, 0);

        int vbase = vb0 + it * 16;
#pragma unroll
        for (int g = 0; g < 2; ++g) {
            unsigned short* dst = g ? z : y;
#pragma unroll
            for (int ct = 0; ct < 2; ++ct) {
                int c = wave * 32 + ct * 16 + l15;
#pragma unroll
                for (int r = 0; r < 4; ++r) {
                    int v = vbase + quad * 4 + r;
                    dst[(size_t)v * HID + c] = f2bf(acc[g][ct][r]);
                }
            }
        }
#pragma unroll
        for (int ks = 0; ks < 5; ++ks) a_cur[ks] = a_nxt[ks];
    }
}

// ---- CSR build (unchanged from round 2) ----
__global__ __launch_bounds__(256) void k_degree(const int* __restrict__ edges,
                                                int* __restrict__ rowstart) {
    int e = blockIdx.x * 256 + threadIdx.x;
    int e0 = edges[2 * e], e1 = edges[2 * e + 1];
    atomicAdd(&rowstart[1 + e0], 1);
    atomicAdd(&rowstart[1 + e1], 1);
}

__global__ __launch_bounds__(256) void k_scan1(const int* __restrict__ rowstart,
                                               int* __restrict__ bsum) {
    __shared__ int s[256];
    int base = blockIdx.x * 1024 + threadIdx.x * 4;
    int t = 0;
#pragma unroll
    for (int j = 0; j < 4; ++j) { int idx = base + j; if (idx <= NV) t += rowstart[idx]; }
    s[threadIdx.x] = t;
    __syncthreads();
    for (int off = 1; off < 256; off <<= 1) {
        int v = (threadIdx.x >= off) ? s[threadIdx.x - off] : 0;
        __syncthreads();
        s[threadIdx.x] += v;
        __syncthreads();
    }
    if (threadIdx.x == 255) bsum[blockIdx.x] = s[255];
}

__global__ __launch_bounds__(512) void k_scan2(const int* __restrict__ bsum,
                                               int* __restrict__ boff) {
    __shared__ int s[512];
    int i = threadIdx.x;
    s[i] = (i < 257) ? bsum[i] : 0;
    __syncthreads();
    for (int off = 1; off < 512; off <<= 1) {
        int v = (i >= off) ? s[i - off] : 0;
        __syncthreads();
        s[i] += v;
        __syncthreads();
    }
    if (i < 257) boff[i] = s[i] - bsum[i];
}

__global__ __launch_bounds__(256) void k_scan3(int* __restrict__ rowstart,
                                               const int* __restrict__ boff,
                                               int* __restrict__ cursor) {
    __shared__ int s[256];
    int base = blockIdx.x * 1024 + threadIdx.x * 4;
    int v[4];
    int t = 0;
#pragma unroll
    for (int j = 0; j < 4; ++j) {
        int idx = base + j;
        v[j] = (idx <= NV) ? rowstart[idx] : 0;
        t += v[j];
    }
    s[threadIdx.x] = t;
    __syncthreads();
    for (int off = 1; off < 256; off <<= 1) {
        int x = (threadIdx.x >= off) ? s[threadIdx.x - off] : 0;
        __syncthreads();
        s[threadIdx.x] += x;
        __syncthreads();
    }
    int run = s[threadIdx.x] - t + boff[blockIdx.x];
#pragma unroll
    for (int j = 0; j < 4; ++j) {
        int idx = base + j;
        run += v[j];
        if (idx <= NV) rowstart[idx] = run;
    }
    (void)cursor;
}

__global__ __launch_bounds__(256) void k_cursor(const int* __restrict__ rowstart,
                                                int* __restrict__ cursor) {
    int v = blockIdx.x * 256 + threadIdx.x;
    cursor[v] = rowstart[v];
}

__global__ __launch_bounds__(256) void k_fill(const int* __restrict__ edges,
                                              int* __restrict__ cursor,
                                              int* __restrict__ adj) {
    int e = blockIdx.x * 256 + threadIdx.x;
    int e0 = edges[2 * e], e1 = edges[2 * e + 1];
    int p0 = atomicAdd(&cursor[e0], 1);
    adj[p0] = e1;
    int p1 = atomicAdd(&cursor[e1], 1);
    adj[p1] = e0;
}

// relu(y[v] + sum_{u in N(v)} z[u]); LAST: write fp32 (stride HID); else bf16 feats (stride KB)
template <bool LAST>
__global__ __launch_bounds__(256) void k_gather(const int* __restrict__ rowstart,
                                                const int* __restrict__ adj,
                                                const unsigned short* __restrict__ zbf,
                                                const unsigned short* __restrict__ ybf,
                                                unsigned short* __restrict__ featdst,
                                                float* __restrict__ accdst,
                                                const float* __restrict__ verts) {
    int v  = blockIdx.x * 8 + (threadIdx.x >> 5);
    int cq = threadIdx.x & 31;
    int start = rowstart[v], end = rowstart[v + 1];
    ushort4 yy = *(const ushort4*)(ybf + (size_t)v * HID + 4 * cq);
    float4 a;
    a.x = bf2f(yy.x); a.y = bf2f(yy.y); a.z = bf2f(yy.z); a.w = bf2f(yy.w);
    for (int n = start; n < end; ++n) {
        int u = adj[n];
        ushort4 zz = *(const ushort4*)(zbf + (size_t)u * HID + 4 * cq);
        a.x += bf2f(zz.x); a.y += bf2f(zz.y);
        a.z += bf2f(zz.z); a.w += bf2f(zz.w);
    }
    a.x = fmaxf(a.x, 0.f); a.y = fmaxf(a.y, 0.f);
    a.z = fmaxf(a.z, 0.f); a.w = fmaxf(a.w, 0.f);
    if (LAST) {
        *(float4*)(accdst + (size_t)v * HID + 4 * cq) = a;
    } else {
        ushort4 o;
        o.x = f2bf(a.x); o.y = f2bf(a.y); o.z = f2bf(a.z); o.w = f2bf(a.w);
        *(ushort4*)(featdst + (size_t)v * KB + 4 * cq) = o;
        if (cq < 8) {
            ushort4 p;
            unsigned short* pv = (unsigned short*)&p;
#pragma unroll
            for (int t = 0; t < 4; ++t) {
                int k = 4 * cq + t;
                pv[t] = (k < 3) ? f2bf(verts[(size_t)v * 3 + k]) : 0;
            }
            *(ushort4*)(featdst + (size_t)v * KB + 128 + 4 * cq) = p;
        }
    }
}

// new_verts = verts + tanh(concat(fin, verts) @ ow + ob)
__global__ __launch_bounds__(256) void k_offset(const float* __restrict__ fin,
                                                const float* __restrict__ verts,
                                                const float* __restrict__ ow,
                                                const float* __restrict__ ob,
                                                float* __restrict__ outp) {
    __shared__ float owl[DIN * 3];
    for (int idx = threadIdx.x; idx < DIN * 3; idx += 256) owl[idx] = ow[idx];
    __syncthreads();
    int v = blockIdx.x * 256 + threadIdx.x;
    const float* f = fin + (size_t)v * HID;
    float d0 = ob[0], d1 = ob[1], d2 = ob[2];
#pragma unroll 8
    for (int q = 0; q < 32; ++q) {
        float4 fl = ((const float4*)f)[q];
#pragma unroll
        for (int j = 0; j < 4; ++j) {
            float fv = ((const float*)&fl)[j];
            int k = 4 * q + j;
            d0 += fv * owl[k * 3 + 0];
            d1 += fv * owl[k * 3 + 1];
            d2 += fv * owl[k * 3 + 2];
        }
    }
    float vx = verts[(size_t)v * 3 + 0];
    float vy = verts[(size_t)v * 3 + 1];
    float vz = verts[(size_t)v * 3 + 2];
    d0 += vx * owl[128 * 3 + 0] + vy * owl[129 * 3 + 0] + vz * owl[130 * 3 + 0];
    d1 += vx * owl[128 * 3 + 1] + vy * owl[129 * 3 + 1] + vz * owl[130 * 3 + 1];
    d2 += vx * owl[128 * 3 + 2] + vy * owl[129 * 3 + 2] + vz * owl[130 * 3 + 2];
    outp[(size_t)v * 3 + 0] = vx + tanhf(d0);
    outp[(size_t)v * 3 + 1] = vy + tanhf(d1);
    outp[(size_t)v * 3 + 2] = vz + tanhf(d2);
}

extern "C" void kernel_launch(void* const* d_in, const int* in_sizes, int n_in,
                              void* d_out, int out_size, void* d_ws, size_t ws_size,
                              hipStream_t stream) {
    const float* x     = (const float*)d_in[0];
    const float* verts = (const float*)d_in[1];
    const int*   edges = (const int*)d_in[2];
    const float* bw    = (const float*)d_in[3];
    const float* bb    = (const float*)d_in[4];
    const float* w0    = (const float*)d_in[5];
    const float* b0    = (const float*)d_in[6];
    const float* w1    = (const float*)d_in[7];
    const float* b1    = (const float*)d_in[8];
    const float* ow    = (const float*)d_in[9];
    const float* ob    = (const float*)d_in[10];
    float* out = (float*)d_out;

    char* w = (char*)d_ws;
    float* P            = (float*)w;           w += (size_t)NPIX * HID * 4;
    unsigned short* feats = (unsigned short*)w; w += (size_t)NV * KB * 2;
    unsigned short* zbf = (unsigned short*)w;  w += (size_t)NV * HID * 2;
    unsigned short* ybf = (unsigned short*)w;  w += (size_t)NV * HID * 2;
    unsigned short* Wt  = (unsigned short*)w;  w += (size_t)6 * 128 * KB * 2;
    int* adj            = (int*)w;             w += (size_t)2 * NE * 4;
    int* rowstart       = (int*)w;             w += (size_t)(NV + 1) * 4;
    int* cursor         = (int*)w;             w += (size_t)NV * 4;
    int* bsum           = (int*)w;             w += 512 * 4;
    int* boff           = (int*)w;             w += 512 * 4;
    float* acc          = out + (size_t)3 * NV;   // final vert_feats_nopos (fp32)

    // CSR build (reused across layers)
    hipMemsetAsync(rowstart, 0, (size_t)(NV + 1) * 4, stream);
    k_degree<<<NE / 256, 256, 0, stream>>>(edges, rowstart);
    k_scan1<<<257, 256, 0, stream>>>(rowstart, bsum);
    k_scan2<<<1, 512, 0, stream>>>(bsum, boff);
    k_scan3<<<257, 256, 0, stream>>>(rowstart, boff, cursor);
    k_cursor<<<NV / 256, 256, 0, stream>>>(rowstart, cursor);
    k_fill<<<NE / 256, 256, 0, stream>>>(edges, cursor, adj);

    k_prepw<<<3, 256, 0, stream>>>(w0, w1, Wt);
    k_project<<<NPIX / 32, 256, 0, stream>>>(x, bw, P);
    k_sample<<<NV / 2, 256, 0, stream>>>(P, verts, bb, feats);

    for (int i = 0; i < 3; ++i) {
        const unsigned short* Wt0 = Wt + (size_t)(2 * i + 0) * 128 * KB;
        const unsigned short* Wt1 = Wt + (size_t)(2 * i + 1) * 128 * KB;
        k_gemm2<<<NV / 256, 256, 0, stream>>>(feats, Wt0, Wt1,
                                              b0 + (size_t)i * HID, b1 + (size_t)i * HID,
                                              ybf, zbf);
        if (i < 2) k_gather<false><<<NV / 8, 256, 0, stream>>>(rowstart, adj, zbf, ybf,
                                                               feats, nullptr, verts);
        else       k_gather<true ><<<NV / 8, 256, 0, stream>>>(rowstart, adj, zbf, ybf,
                                                               nullptr, acc, verts);
    }
    k_offset<<<NV / 256, 256, 0, stream>>>(acc, verts, ow, ob, out);
}

// Round 4
// 989.541 us; speedup vs baseline: 10.1655x; 1.2566x over previous
//
#include <hip/hip_runtime.h>
#include <cmath>

#define NV   262144
#define NE   786432
#define CIMG 256
#define HID  128
#define NPIX 4096
#define DIN  131
#define KB   160    // bf16 feats padded K (131 -> 160, zeros)

typedef short bf8v __attribute__((ext_vector_type(8)));
typedef float f4v  __attribute__((ext_vector_type(4)));
typedef unsigned short u16x8 __attribute__((ext_vector_type(8)));

__device__ __forceinline__ unsigned short f2bf(float v) {
    unsigned int u = __float_as_uint(v);
    u = u + 0x7fffu + ((u >> 16) & 1u);   // RNE
    return (unsigned short)(u >> 16);
}
__device__ __forceinline__ float bf2f(unsigned short b) {
    return __uint_as_float(((unsigned int)b) << 16);
}

// P[p][j] = sum_c img[c][p] * bw[c][j]; 8 pixels/block, 512 blocks.
__global__ __launch_bounds__(256) void k_project(const float* __restrict__ img,
                                                 const float* __restrict__ bw,
                                                 float* __restrict__ P) {
    int j  = threadIdx.x & 127;
    int pr = threadIdx.x >> 7;               // 0..1
    int pbase = blockIdx.x * 8 + pr * 4;     // 4 pixels per thread
    float4 a = {0.f, 0.f, 0.f, 0.f};
#pragma unroll 4
    for (int c = 0; c < CIMG; ++c) {
        float bwv = bw[c * HID + j];
        float4 iv = *(const float4*)(img + (size_t)c * NPIX + pbase);
        a.x += iv.x * bwv; a.y += iv.y * bwv;
        a.z += iv.z * bwv; a.w += iv.w * bwv;
    }
    P[(size_t)(pbase + 0) * HID + j] = a.x;
    P[(size_t)(pbase + 1) * HID + j] = a.y;
    P[(size_t)(pbase + 2) * HID + j] = a.z;
    P[(size_t)(pbase + 3) * HID + j] = a.w;
}

// feats[v][0..127] = relu(bilerp + bb) bf16; [128..130]=verts; [131..159]=0
__global__ __launch_bounds__(256) void k_sample(const float* __restrict__ P,
                                                const float* __restrict__ verts,
                                                const float* __restrict__ bb,
                                                unsigned short* __restrict__ feats) {
    int c = threadIdx.x & (HID - 1);
    int v = blockIdx.x * 2 + (threadIdx.x >> 7);
    float vx = verts[(size_t)v * 3 + 0];
    float vy = verts[(size_t)v * 3 + 1];
    float px = (vx + 1.f) * 31.5f;
    float py = (vy + 1.f) * 31.5f;
    float x0f = floorf(px), y0f = floorf(py);
    float wx = px - x0f,   wy = py - y0f;
    int x0 = (int)x0f, y0 = (int)y0f;
    int x0i = min(max(x0, 0), 63);
    int x1i = min(x0i + 1, 63);
    int y0i = min(max(y0, 0), 63);
    int y1i = min(y0i + 1, 63);
    const float* p00 = P + (size_t)(y0i * 64 + x0i) * HID;
    const float* p01 = P + (size_t)(y0i * 64 + x1i) * HID;
    const float* p10 = P + (size_t)(y1i * 64 + x0i) * HID;
    const float* p11 = P + (size_t)(y1i * 64 + x1i) * HID;
    float v00 = p00[c], v01 = p01[c], v10 = p10[c], v11 = p11[c];
    float top = v00 * (1.f - wx) + v01 * wx;
    float bot = v10 * (1.f - wx) + v11 * wx;
    float h = fmaxf(top * (1.f - wy) + bot * wy + bb[c], 0.f);
    unsigned short* fr = feats + (size_t)v * KB;
    fr[c] = f2bf(h);
    if (c < 32) {
        float val = (c < 3) ? verts[(size_t)v * 3 + c] : 0.f;
        fr[128 + c] = f2bf(val);
    }
}

// Wt[m][n][k] bf16, m = layer*2+g, transposed from W[k][n], zero-padded k>=131
__global__ __launch_bounds__(256) void k_prepw(const float* __restrict__ w0,
                                               const float* __restrict__ w1,
                                               unsigned short* __restrict__ Wt) {
    int idx = blockIdx.x * 256 + threadIdx.x;
    if (idx >= 6 * 128) return;
    int m = idx >> 7;
    int n = idx & 127;
    int layer = m >> 1, g = m & 1;
    const float* W = (g ? w1 : w0) + (size_t)layer * DIN * HID;
    unsigned short* dst = Wt + (size_t)(m * 128 + n) * KB;
    for (int k = 0; k < KB; ++k) {
        float v = (k < DIN) ? W[(size_t)k * HID + n] : 0.f;
        dst[k] = f2bf(v);
    }
}

// Fused MFMA GEMM: y = feats@W0+b0 (bf16), z = feats@W1+b1 (bf16).
__global__ __launch_bounds__(256, 2) void k_gemm2(const unsigned short* __restrict__ feats,
                                                  const unsigned short* __restrict__ Wt0,
                                                  const unsigned short* __restrict__ Wt1,
                                                  const float* __restrict__ bias0,
                                                  const float* __restrict__ bias1,
                                                  unsigned short* __restrict__ y,
                                                  unsigned short* __restrict__ z) {
    int lane = threadIdx.x & 63;
    int wave = threadIdx.x >> 6;     // column quarter: cols 32*wave..+31
    int l15  = lane & 15;
    int quad = lane >> 4;

    bf8v bfrag[2][2][5];
#pragma unroll
    for (int g = 0; g < 2; ++g) {
        const unsigned short* Wg = g ? Wt1 : Wt0;
#pragma unroll
        for (int ct = 0; ct < 2; ++ct) {
            int n = wave * 32 + ct * 16 + l15;
#pragma unroll
            for (int ks = 0; ks < 5; ++ks)
                bfrag[g][ct][ks] = *(const bf8v*)(Wg + (size_t)n * KB + ks * 32 + quad * 8);
        }
    }
    float bv[2][2];
#pragma unroll
    for (int g = 0; g < 2; ++g)
#pragma unroll
        for (int ct = 0; ct < 2; ++ct)
            bv[g][ct] = (g ? bias1 : bias0)[wave * 32 + ct * 16 + l15];

    int vb0 = blockIdx.x * 256;
    bf8v a_cur[5], a_nxt[5];
    {
        const unsigned short* ap = feats + (size_t)(vb0 + l15) * KB + quad * 8;
#pragma unroll
        for (int ks = 0; ks < 5; ++ks) a_cur[ks] = *(const bf8v*)(ap + ks * 32);
    }

    for (int it = 0; it < 16; ++it) {
        if (it < 15) {
            const unsigned short* ap = feats + (size_t)(vb0 + (it + 1) * 16 + l15) * KB + quad * 8;
#pragma unroll
            for (int ks = 0; ks < 5; ++ks) a_nxt[ks] = *(const bf8v*)(ap + ks * 32);
        }
        f4v acc[2][2];
#pragma unroll
        for (int g = 0; g < 2; ++g)
#pragma unroll
            for (int ct = 0; ct < 2; ++ct) {
                f4v t = {bv[g][ct], bv[g][ct], bv[g][ct], bv[g][ct]};
                acc[g][ct] = t;
            }
#pragma unroll
        for (int ks = 0; ks < 5; ++ks)
#pragma unroll
            for (int g = 0; g < 2; ++g)
#pragma unroll
                for (int ct = 0; ct < 2; ++ct)
                    acc[g][ct] = __builtin_amdgcn_mfma_f32_16x16x32_bf16(
                        a_cur[ks], bfrag[g][ct][ks], acc[g][ct], 0, 0, 0);

        int vbase = vb0 + it * 16;
#pragma unroll
        for (int g = 0; g < 2; ++g) {
            unsigned short* dst = g ? z : y;
#pragma unroll
            for (int ct = 0; ct < 2; ++ct) {
                int c = wave * 32 + ct * 16 + l15;
#pragma unroll
                for (int r = 0; r < 4; ++r) {
                    int v = vbase + quad * 4 + r;
                    dst[(size_t)v * HID + c] = f2bf(acc[g][ct][r]);
                }
            }
        }
#pragma unroll
        for (int ks = 0; ks < 5; ++ks) a_cur[ks] = a_nxt[ks];
    }
}

// ---- CSR build ----
__global__ __launch_bounds__(256) void k_degree(const int* __restrict__ edges,
                                                int* __restrict__ rowstart) {
    int e = blockIdx.x * 256 + threadIdx.x;
    int e0 = edges[2 * e], e1 = edges[2 * e + 1];
    atomicAdd(&rowstart[1 + e0], 1);
    atomicAdd(&rowstart[1 + e1], 1);
}

__global__ __launch_bounds__(256) void k_scan1(const int* __restrict__ rowstart,
                                               int* __restrict__ bsum) {
    __shared__ int s[256];
    int base = blockIdx.x * 1024 + threadIdx.x * 4;
    int t = 0;
#pragma unroll
    for (int j = 0; j < 4; ++j) { int idx = base + j; if (idx <= NV) t += rowstart[idx]; }
    s[threadIdx.x] = t;
    __syncthreads();
    for (int off = 1; off < 256; off <<= 1) {
        int v = (threadIdx.x >= off) ? s[threadIdx.x - off] : 0;
        __syncthreads();
        s[threadIdx.x] += v;
        __syncthreads();
    }
    if (threadIdx.x == 255) bsum[blockIdx.x] = s[255];
}

__global__ __launch_bounds__(512) void k_scan2(const int* __restrict__ bsum,
                                               int* __restrict__ boff) {
    __shared__ int s[512];
    int i = threadIdx.x;
    s[i] = (i < 257) ? bsum[i] : 0;
    __syncthreads();
    for (int off = 1; off < 512; off <<= 1) {
        int v = (i >= off) ? s[i - off] : 0;
        __syncthreads();
        s[i] += v;
        __syncthreads();
    }
    if (i < 257) boff[i] = s[i] - bsum[i];
}

// inclusive scan of 1024-chunks + boff; rowstart[idx] final; cursor[idx] = rowstart[idx]
__global__ __launch_bounds__(256) void k_scan3(int* __restrict__ rowstart,
                                               const int* __restrict__ boff,
                                               int* __restrict__ cursor) {
    __shared__ int s[256];
    int base = blockIdx.x * 1024 + threadIdx.x * 4;
    int v[4];
    int t = 0;
#pragma unroll
    for (int j = 0; j < 4; ++j) {
        int idx = base + j;
        v[j] = (idx <= NV) ? rowstart[idx] : 0;
        t += v[j];
    }
    s[threadIdx.x] = t;
    __syncthreads();
    for (int off = 1; off < 256; off <<= 1) {
        int x = (threadIdx.x >= off) ? s[threadIdx.x - off] : 0;
        __syncthreads();
        s[threadIdx.x] += x;
        __syncthreads();
    }
    int run = s[threadIdx.x] - t + boff[blockIdx.x];
#pragma unroll
    for (int j = 0; j < 4; ++j) {
        int idx = base + j;
        run += v[j];
        if (idx <= NV) {
            rowstart[idx] = run;
            if (idx < NV) cursor[idx] = run;
        }
    }
}

__global__ __launch_bounds__(256) void k_fill(const int* __restrict__ edges,
                                              int* __restrict__ cursor,
                                              int* __restrict__ adj) {
    int e = blockIdx.x * 256 + threadIdx.x;
    int e0 = edges[2 * e], e1 = edges[2 * e + 1];
    int p0 = atomicAdd(&cursor[e0], 1);
    adj[p0] = e1;
    int p1 = atomicAdd(&cursor[e1], 1);
    adj[p1] = e0;
}

// relu(y[v] + sum_{u in N(v)} z[u]); 16 lanes/vertex, 16B loads.
// LAST: write fp32 (stride HID); else bf16 feats (stride KB) + verts tail.
template <bool LAST>
__global__ __launch_bounds__(256) void k_gather(const int* __restrict__ rowstart,
                                                const int* __restrict__ adj,
                                                const unsigned short* __restrict__ zbf,
                                                const unsigned short* __restrict__ ybf,
                                                unsigned short* __restrict__ featdst,
                                                float* __restrict__ accdst,
                                                const float* __restrict__ verts) {
    int cq = threadIdx.x & 15;                 // 8 channels: 8*cq..8*cq+7
    int v  = blockIdx.x * 16 + (threadIdx.x >> 4);
    int start = rowstart[v], end = rowstart[v + 1];
    u16x8 yy = *(const u16x8*)(ybf + (size_t)v * HID + 8 * cq);
    float a[8];
#pragma unroll
    for (int i = 0; i < 8; ++i) a[i] = bf2f(yy[i]);
    for (int n = start; n < end; ++n) {
        int u = adj[n];
        u16x8 zz = *(const u16x8*)(zbf + (size_t)u * HID + 8 * cq);
#pragma unroll
        for (int i = 0; i < 8; ++i) a[i] += bf2f(zz[i]);
    }
#pragma unroll
    for (int i = 0; i < 8; ++i) a[i] = fmaxf(a[i], 0.f);
    if (LAST) {
        float4 lo = {a[0], a[1], a[2], a[3]};
        float4 hi = {a[4], a[5], a[6], a[7]};
        float* dst = accdst + (size_t)v * HID + 8 * cq;
        *(float4*)(dst + 0) = lo;
        *(float4*)(dst + 4) = hi;
    } else {
        u16x8 o;
#pragma unroll
        for (int i = 0; i < 8; ++i) o[i] = f2bf(a[i]);
        *(u16x8*)(featdst + (size_t)v * KB + 8 * cq) = o;
        if (cq < 4) {
            u16x8 p;
#pragma unroll
            for (int t = 0; t < 8; ++t) {
                int k = 128 + 8 * cq + t;
                p[t] = (k < DIN) ? f2bf(verts[(size_t)v * 3 + (k - 128)]) : (unsigned short)0;
            }
            *(u16x8*)(featdst + (size_t)v * KB + 128 + 8 * cq) = p;
        }
    }
}

// new_verts = verts + tanh(concat(fin, verts) @ ow + ob)
__global__ __launch_bounds__(256) void k_offset(const float* __restrict__ fin,
                                                const float* __restrict__ verts,
                                                const float* __restrict__ ow,
                                                const float* __restrict__ ob,
                                                float* __restrict__ outp) {
    __shared__ float owl[DIN * 3];
    for (int idx = threadIdx.x; idx < DIN * 3; idx += 256) owl[idx] = ow[idx];
    __syncthreads();
    int v = blockIdx.x * 256 + threadIdx.x;
    const float* f = fin + (size_t)v * HID;
    float d0 = ob[0], d1 = ob[1], d2 = ob[2];
#pragma unroll 8
    for (int q = 0; q < 32; ++q) {
        float4 fl = ((const float4*)f)[q];
#pragma unroll
        for (int j = 0; j < 4; ++j) {
            float fv = ((const float*)&fl)[j];
            int k = 4 * q + j;
            d0 += fv * owl[k * 3 + 0];
            d1 += fv * owl[k * 3 + 1];
            d2 += fv * owl[k * 3 + 2];
        }
    }
    float vx = verts[(size_t)v * 3 + 0];
    float vy = verts[(size_t)v * 3 + 1];
    float vz = verts[(size_t)v * 3 + 2];
    d0 += vx * owl[128 * 3 + 0] + vy * owl[129 * 3 + 0] + vz * owl[130 * 3 + 0];
    d1 += vx * owl[128 * 3 + 1] + vy * owl[129 * 3 + 1] + vz * owl[130 * 3 + 1];
    d2 += vx * owl[128 * 3 + 2] + vy * owl[129 * 3 + 2] + vz * owl[130 * 3 + 2];
    outp[(size_t)v * 3 + 0] = vx + tanhf(d0);
    outp[(size_t)v * 3 + 1] = vy + tanhf(d1);
    outp[(size_t)v * 3 + 2] = vz + tanhf(d2);
}

extern "C" void kernel_launch(void* const* d_in, const int* in_sizes, int n_in,
                              void* d_out, int out_size, void* d_ws, size_t ws_size,
                              hipStream_t stream) {
    const float* x     = (const float*)d_in[0];
    const float* verts = (const float*)d_in[1];
    const int*   edges = (const int*)d_in[2];
    const float* bw    = (const float*)d_in[3];
    const float* bb    = (const float*)d_in[4];
    const float* w0    = (const float*)d_in[5];
    const float* b0    = (const float*)d_in[6];
    const float* w1    = (const float*)d_in[7];
    const float* b1    = (const float*)d_in[8];
    const float* ow    = (const float*)d_in[9];
    const float* ob    = (const float*)d_in[10];
    float* out = (float*)d_out;

    char* w = (char*)d_ws;
    float* P              = (float*)w;          w += (size_t)NPIX * HID * 4;
    unsigned short* feats = (unsigned short*)w; w += (size_t)NV * KB * 2;
    unsigned short* zbf   = (unsigned short*)w; w += (size_t)NV * HID * 2;
    unsigned short* ybf   = (unsigned short*)w; w += (size_t)NV * HID * 2;
    unsigned short* Wt    = (unsigned short*)w; w += (size_t)6 * 128 * KB * 2;
    int* adj              = (int*)w;            w += (size_t)2 * NE * 4;
    int* rowstart         = (int*)w;            w += (size_t)(NV + 1) * 4;
    int* cursor           = (int*)w;            w += (size_t)NV * 4;
    int* bsum             = (int*)w;            w += 512 * 4;
    int* boff             = (int*)w;            w += 512 * 4;
    float* acc            = out + (size_t)3 * NV;   // final vert_feats_nopos (fp32)

    // CSR build (reused across layers)
    hipMemsetAsync(rowstart, 0, (size_t)(NV + 1) * 4, stream);
    k_degree<<<NE / 256, 256, 0, stream>>>(edges, rowstart);
    k_scan1<<<257, 256, 0, stream>>>(rowstart, bsum);
    k_scan2<<<1, 512, 0, stream>>>(bsum, boff);
    k_scan3<<<257, 256, 0, stream>>>(rowstart, boff, cursor);
    k_fill<<<NE / 256, 256, 0, stream>>>(edges, cursor, adj);

    k_prepw<<<3, 256, 0, stream>>>(w0, w1, Wt);
    k_project<<<NPIX / 8, 256, 0, stream>>>(x, bw, P);
    k_sample<<<NV / 2, 256, 0, stream>>>(P, verts, bb, feats);

    for (int i = 0; i < 3; ++i) {
        const unsigned short* Wt0 = Wt + (size_t)(2 * i + 0) * 128 * KB;
        const unsigned short* Wt1 = Wt + (size_t)(2 * i + 1) * 128 * KB;
        k_gemm2<<<NV / 256, 256, 0, stream>>>(feats, Wt0, Wt1,
                                              b0 + (size_t)i * HID, b1 + (size_t)i * HID,
                                              ybf, zbf);
        if (i < 2) k_gather<false><<<NV / 16, 256, 0, stream>>>(rowstart, adj, zbf, ybf,
                                                                feats, nullptr, verts);
        else       k_gather<true ><<<NV / 16, 256, 0, stream>>>(rowstart, adj, zbf, ybf,
                                                                nullptr, acc, verts);
    }
    k_offset<<<NV / 256, 256, 0, stream>>>(acc, verts, ow, ob, out);
}

// Round 5
// 804.778 us; speedup vs baseline: 12.4994x; 1.2296x over previous
//
#include <hip/hip_runtime.h>
#include <cmath>

#define NV   262144
#define NE   786432
#define CIMG 256
#define HID  128
#define NPIX 4096
#define DIN  131
#define KB   160    // bf16 feats padded K (131 -> 160, zeros)
#define NBKT 256    // coarse buckets for CSR build (1024 vertices each)

typedef short bf8v __attribute__((ext_vector_type(8)));
typedef float f4v  __attribute__((ext_vector_type(4)));
typedef unsigned short u16x8 __attribute__((ext_vector_type(8)));

__device__ __forceinline__ unsigned short f2bf(float v) {
    unsigned int u = __float_as_uint(v);
    u = u + 0x7fffu + ((u >> 16) & 1u);   // RNE
    return (unsigned short)(u >> 16);
}
__device__ __forceinline__ float bf2f(unsigned short b) {
    return __uint_as_float(((unsigned int)b) << 16);
}

// P[p][j] = sum_c img[c][p] * bw[c][j]; 8 pixels/block, 512 blocks.
__global__ __launch_bounds__(256) void k_project(const float* __restrict__ img,
                                                 const float* __restrict__ bw,
                                                 float* __restrict__ P) {
    int j  = threadIdx.x & 127;
    int pr = threadIdx.x >> 7;
    int pbase = blockIdx.x * 8 + pr * 4;
    float4 a = {0.f, 0.f, 0.f, 0.f};
#pragma unroll 4
    for (int c = 0; c < CIMG; ++c) {
        float bwv = bw[c * HID + j];
        float4 iv = *(const float4*)(img + (size_t)c * NPIX + pbase);
        a.x += iv.x * bwv; a.y += iv.y * bwv;
        a.z += iv.z * bwv; a.w += iv.w * bwv;
    }
    P[(size_t)(pbase + 0) * HID + j] = a.x;
    P[(size_t)(pbase + 1) * HID + j] = a.y;
    P[(size_t)(pbase + 2) * HID + j] = a.z;
    P[(size_t)(pbase + 3) * HID + j] = a.w;
}

// feats[v][0..127] = relu(bilerp + bb) bf16; [128..130]=verts; [131..159]=0
__global__ __launch_bounds__(256) void k_sample(const float* __restrict__ P,
                                                const float* __restrict__ verts,
                                                const float* __restrict__ bb,
                                                unsigned short* __restrict__ feats) {
    int c = threadIdx.x & (HID - 1);
    int v = blockIdx.x * 2 + (threadIdx.x >> 7);
    float vx = verts[(size_t)v * 3 + 0];
    float vy = verts[(size_t)v * 3 + 1];
    float px = (vx + 1.f) * 31.5f;
    float py = (vy + 1.f) * 31.5f;
    float x0f = floorf(px), y0f = floorf(py);
    float wx = px - x0f,   wy = py - y0f;
    int x0 = (int)x0f, y0 = (int)y0f;
    int x0i = min(max(x0, 0), 63);
    int x1i = min(x0i + 1, 63);
    int y0i = min(max(y0, 0), 63);
    int y1i = min(y0i + 1, 63);
    const float* p00 = P + (size_t)(y0i * 64 + x0i) * HID;
    const float* p01 = P + (size_t)(y0i * 64 + x1i) * HID;
    const float* p10 = P + (size_t)(y1i * 64 + x0i) * HID;
    const float* p11 = P + (size_t)(y1i * 64 + x1i) * HID;
    float v00 = p00[c], v01 = p01[c], v10 = p10[c], v11 = p11[c];
    float top = v00 * (1.f - wx) + v01 * wx;
    float bot = v10 * (1.f - wx) + v11 * wx;
    float h = fmaxf(top * (1.f - wy) + bot * wy + bb[c], 0.f);
    unsigned short* fr = feats + (size_t)v * KB;
    fr[c] = f2bf(h);
    if (c < 32) {
        float val = (c < 3) ? verts[(size_t)v * 3 + c] : 0.f;
        fr[128 + c] = f2bf(val);
    }
}

// Wt[m][n][k] bf16, m = layer*2+g, transposed from W[k][n], zero-padded k>=131
__global__ __launch_bounds__(256) void k_prepw(const float* __restrict__ w0,
                                               const float* __restrict__ w1,
                                               unsigned short* __restrict__ Wt) {
    int idx = blockIdx.x * 256 + threadIdx.x;
    if (idx >= 6 * 128) return;
    int m = idx >> 7;
    int n = idx & 127;
    int layer = m >> 1, g = m & 1;
    const float* W = (g ? w1 : w0) + (size_t)layer * DIN * HID;
    unsigned short* dst = Wt + (size_t)(m * 128 + n) * KB;
    for (int k = 0; k < KB; ++k) {
        float v = (k < DIN) ? W[(size_t)k * HID + n] : 0.f;
        dst[k] = f2bf(v);
    }
}

// Fused MFMA GEMM: y = feats@W0+b0 (bf16), z = feats@W1+b1 (bf16).
__global__ __launch_bounds__(256, 2) void k_gemm2(const unsigned short* __restrict__ feats,
                                                  const unsigned short* __restrict__ Wt0,
                                                  const unsigned short* __restrict__ Wt1,
                                                  const float* __restrict__ bias0,
                                                  const float* __restrict__ bias1,
                                                  unsigned short* __restrict__ y,
                                                  unsigned short* __restrict__ z) {
    int lane = threadIdx.x & 63;
    int wave = threadIdx.x >> 6;
    int l15  = lane & 15;
    int quad = lane >> 4;

    bf8v bfrag[2][2][5];
#pragma unroll
    for (int g = 0; g < 2; ++g) {
        const unsigned short* Wg = g ? Wt1 : Wt0;
#pragma unroll
        for (int ct = 0; ct < 2; ++ct) {
            int n = wave * 32 + ct * 16 + l15;
#pragma unroll
            for (int ks = 0; ks < 5; ++ks)
                bfrag[g][ct][ks] = *(const bf8v*)(Wg + (size_t)n * KB + ks * 32 + quad * 8);
        }
    }
    float bv[2][2];
#pragma unroll
    for (int g = 0; g < 2; ++g)
#pragma unroll
        for (int ct = 0; ct < 2; ++ct)
            bv[g][ct] = (g ? bias1 : bias0)[wave * 32 + ct * 16 + l15];

    int vb0 = blockIdx.x * 256;
    bf8v a_cur[5], a_nxt[5];
    {
        const unsigned short* ap = feats + (size_t)(vb0 + l15) * KB + quad * 8;
#pragma unroll
        for (int ks = 0; ks < 5; ++ks) a_cur[ks] = *(const bf8v*)(ap + ks * 32);
    }

    for (int it = 0; it < 16; ++it) {
        if (it < 15) {
            const unsigned short* ap = feats + (size_t)(vb0 + (it + 1) * 16 + l15) * KB + quad * 8;
#pragma unroll
            for (int ks = 0; ks < 5; ++ks) a_nxt[ks] = *(const bf8v*)(ap + ks * 32);
        }
        f4v acc[2][2];
#pragma unroll
        for (int g = 0; g < 2; ++g)
#pragma unroll
            for (int ct = 0; ct < 2; ++ct) {
                f4v t = {bv[g][ct], bv[g][ct], bv[g][ct], bv[g][ct]};
                acc[g][ct] = t;
            }
#pragma unroll
        for (int ks = 0; ks < 5; ++ks)
#pragma unroll
            for (int g = 0; g < 2; ++g)
#pragma unroll
                for (int ct = 0; ct < 2; ++ct)
                    acc[g][ct] = __builtin_amdgcn_mfma_f32_16x16x32_bf16(
                        a_cur[ks], bfrag[g][ct][ks], acc[g][ct], 0, 0, 0);

        int vbase = vb0 + it * 16;
#pragma unroll
        for (int g = 0; g < 2; ++g) {
            unsigned short* dst = g ? z : y;
#pragma unroll
            for (int ct = 0; ct < 2; ++ct) {
                int c = wave * 32 + ct * 16 + l15;
#pragma unroll
                for (int r = 0; r < 4; ++r) {
                    int v = vbase + quad * 4 + r;
                    dst[(size_t)v * HID + c] = f2bf(acc[g][ct][r]);
                }
            }
        }
#pragma unroll
        for (int ks = 0; ks < 5; ++ks) a_cur[ks] = a_nxt[ks];
    }
}

// ---- CSR build via 2-level bucket sort (no random 4B scatter) ----
// item = (lv<<18)|u, lv = v&1023, bucket = v>>10

// 384 blocks x 2048 edges: LDS histogram -> 256 global atomics/block
__global__ __launch_bounds__(256) void k_hist(const int4* __restrict__ edges4,
                                              int* __restrict__ gcount) {
    __shared__ int hist[NBKT];
    if (threadIdx.x < NBKT) hist[threadIdx.x] = 0;
    __syncthreads();
#pragma unroll
    for (int i = 0; i < 4; ++i) {
        int4 e = edges4[(size_t)blockIdx.x * 1024 + i * 256 + threadIdx.x];
        atomicAdd(&hist[e.x >> 10], 1);
        atomicAdd(&hist[e.y >> 10], 1);
        atomicAdd(&hist[e.z >> 10], 1);
        atomicAdd(&hist[e.w >> 10], 1);
    }
    __syncthreads();
    if (threadIdx.x < NBKT) atomicAdd(&gcount[threadIdx.x], hist[threadIdx.x]);
}

// single block: exclusive scan of gcount -> bbase, bcur; bbase[256]=2E; rowstart[NV]=2E
__global__ __launch_bounds__(256) void k_scan256(const int* __restrict__ gcount,
                                                 int* __restrict__ bbase,
                                                 int* __restrict__ bcur,
                                                 int* __restrict__ rowstart) {
    __shared__ int s[NBKT];
    int t = threadIdx.x;
    int c = gcount[t];
    s[t] = c;
    __syncthreads();
    for (int off = 1; off < NBKT; off <<= 1) {
        int v = (t >= off) ? s[t - off] : 0;
        __syncthreads();
        s[t] += v;
        __syncthreads();
    }
    bbase[t] = s[t] - c;
    bcur[t]  = s[t] - c;
    if (t == NBKT - 1) {
        bbase[NBKT] = s[t];
        rowstart[NV] = s[t];
    }
}

// block-local counting sort into buckets; reserve contiguous global runs; dense writes
__global__ __launch_bounds__(256) void k_binA(const int4* __restrict__ edges4,
                                              int* __restrict__ bcur,
                                              unsigned int* __restrict__ items) {
    __shared__ int hist[NBKT];
    __shared__ int loff[NBKT];
    __shared__ int gbase[NBKT];
    __shared__ int sscan[256];
    __shared__ unsigned int staged[4096];
    __shared__ unsigned char staged_b[4096];

    if (threadIdx.x < NBKT) hist[threadIdx.x] = 0;
    __syncthreads();

    int vv[16], uu[16], rk[16];
#pragma unroll
    for (int i = 0; i < 4; ++i) {
        int4 e = edges4[(size_t)blockIdx.x * 1024 + i * 256 + threadIdx.x];
        vv[4*i+0] = e.x; uu[4*i+0] = e.y;
        vv[4*i+1] = e.y; uu[4*i+1] = e.x;
        vv[4*i+2] = e.z; uu[4*i+2] = e.w;
        vv[4*i+3] = e.w; uu[4*i+3] = e.z;
    }
#pragma unroll
    for (int i = 0; i < 16; ++i) rk[i] = atomicAdd(&hist[vv[i] >> 10], 1);
    __syncthreads();
    // exclusive scan of hist -> loff
    {
        int t = threadIdx.x;
        int c = hist[t];
        sscan[t] = c;
        __syncthreads();
        for (int off = 1; off < 256; off <<= 1) {
            int x = (t >= off) ? sscan[t - off] : 0;
            __syncthreads();
            sscan[t] += x;
            __syncthreads();
        }
        loff[t] = sscan[t] - c;
    }
    __syncthreads();
#pragma unroll
    for (int i = 0; i < 16; ++i) {
        int b = vv[i] >> 10;
        int pos = loff[b] + rk[i];
        staged[pos] = ((unsigned int)(vv[i] & 1023) << 18) | (unsigned int)uu[i];
        staged_b[pos] = (unsigned char)b;
    }
    __syncthreads();
    if (threadIdx.x < NBKT)
        gbase[threadIdx.x] = atomicAdd(&bcur[threadIdx.x], hist[threadIdx.x]);
    __syncthreads();
#pragma unroll
    for (int i = 0; i < 16; ++i) {
        int s = i * 256 + threadIdx.x;
        int b = staged_b[s];
        items[(size_t)gbase[b] + (s - loff[b])] = staged[s];
    }
}

// one block per bucket: per-vertex count + LDS scan -> rowstart; place adj (L2-local)
__global__ __launch_bounds__(256) void k_binB(const unsigned int* __restrict__ items,
                                              const int* __restrict__ bbase,
                                              int* __restrict__ rowstart,
                                              int* __restrict__ adj) {
    __shared__ int cnt[1024];
    __shared__ int sscan[256];
    int b = blockIdx.x;
    int base = bbase[b];
    int size = bbase[b + 1] - base;
#pragma unroll
    for (int i = 0; i < 4; ++i) cnt[i * 256 + threadIdx.x] = 0;
    __syncthreads();
    for (int i = threadIdx.x; i < size; i += 256) {
        unsigned int it = items[(size_t)base + i];
        atomicAdd(&cnt[(it >> 18) & 1023], 1);
    }
    __syncthreads();
    // scan 1024 with 256 threads (4 each), write rowstart, reset cnt to excl
    {
        int j = threadIdx.x;
        int c[4], t = 0;
#pragma unroll
        for (int i = 0; i < 4; ++i) { c[i] = cnt[4 * j + i]; t += c[i]; }
        sscan[j] = t;
        __syncthreads();
        for (int off = 1; off < 256; off <<= 1) {
            int x = (j >= off) ? sscan[j - off] : 0;
            __syncthreads();
            sscan[j] += x;
            __syncthreads();
        }
        int pre = sscan[j] - t;
#pragma unroll
        for (int i = 0; i < 4; ++i) {
            cnt[4 * j + i] = pre;                       // cursor = exclusive offset
            rowstart[b * 1024 + 4 * j + i] = base + pre;
            pre += c[i];
        }
    }
    __syncthreads();
    for (int i = threadIdx.x; i < size; i += 256) {
        unsigned int it = items[(size_t)base + i];
        int lv = (it >> 18) & 1023;
        int rel = atomicAdd(&cnt[lv], 1);
        adj[base + rel] = (int)(it & 0x3FFFFu);
    }
}

// relu(y[v] + sum_{u in N(v)} z[u]); 16 lanes/vertex, 16B loads.
// LAST: write fp32 acc + fused offset head (tanh deform) ; else bf16 feats.
template <bool LAST>
__global__ __launch_bounds__(256) void k_gather(const int* __restrict__ rowstart,
                                                const int* __restrict__ adj,
                                                const unsigned short* __restrict__ zbf,
                                                const unsigned short* __restrict__ ybf,
                                                unsigned short* __restrict__ featdst,
                                                float* __restrict__ accdst,
                                                const float* __restrict__ verts,
                                                const float* __restrict__ ow,
                                                const float* __restrict__ ob,
                                                float* __restrict__ outp) {
    __shared__ float owl[DIN * 3];
    if (LAST) {
        for (int idx = threadIdx.x; idx < DIN * 3; idx += 256) owl[idx] = ow[idx];
        __syncthreads();
    }
    int cq = threadIdx.x & 15;                 // 8 channels: 8*cq..8*cq+7
    int v  = blockIdx.x * 16 + (threadIdx.x >> 4);
    int start = rowstart[v], end = rowstart[v + 1];
    u16x8 yy = *(const u16x8*)(ybf + (size_t)v * HID + 8 * cq);
    float a[8];
#pragma unroll
    for (int i = 0; i < 8; ++i) a[i] = bf2f(yy[i]);
    for (int n = start; n < end; ++n) {
        int u = adj[n];
        u16x8 zz = *(const u16x8*)(zbf + (size_t)u * HID + 8 * cq);
#pragma unroll
        for (int i = 0; i < 8; ++i) a[i] += bf2f(zz[i]);
    }
#pragma unroll
    for (int i = 0; i < 8; ++i) a[i] = fmaxf(a[i], 0.f);
    if (LAST) {
        float4 lo = {a[0], a[1], a[2], a[3]};
        float4 hi = {a[4], a[5], a[6], a[7]};
        float* dst = accdst + (size_t)v * HID + 8 * cq;
        *(float4*)(dst + 0) = lo;
        *(float4*)(dst + 4) = hi;
        // fused offset head: partial dots + 16-lane reduction
        float d0 = 0.f, d1 = 0.f, d2 = 0.f;
#pragma unroll
        for (int i = 0; i < 8; ++i) {
            int k = 8 * cq + i;
            d0 += a[i] * owl[k * 3 + 0];
            d1 += a[i] * owl[k * 3 + 1];
            d2 += a[i] * owl[k * 3 + 2];
        }
#pragma unroll
        for (int off = 8; off > 0; off >>= 1) {
            d0 += __shfl_down(d0, off, 16);
            d1 += __shfl_down(d1, off, 16);
            d2 += __shfl_down(d2, off, 16);
        }
        if (cq == 0) {
            float vx = verts[(size_t)v * 3 + 0];
            float vy = verts[(size_t)v * 3 + 1];
            float vz = verts[(size_t)v * 3 + 2];
            d0 += vx * owl[128*3+0] + vy * owl[129*3+0] + vz * owl[130*3+0] + ob[0];
            d1 += vx * owl[128*3+1] + vy * owl[129*3+1] + vz * owl[130*3+1] + ob[1];
            d2 += vx * owl[128*3+2] + vy * owl[129*3+2] + vz * owl[130*3+2] + ob[2];
            outp[(size_t)v * 3 + 0] = vx + tanhf(d0);
            outp[(size_t)v * 3 + 1] = vy + tanhf(d1);
            outp[(size_t)v * 3 + 2] = vz + tanhf(d2);
        }
    } else {
        u16x8 o;
#pragma unroll
        for (int i = 0; i < 8; ++i) o[i] = f2bf(a[i]);
        *(u16x8*)(featdst + (size_t)v * KB + 8 * cq) = o;
        // verts tail rows [128..160) persist from k_sample — no rewrite needed
    }
}

extern "C" void kernel_launch(void* const* d_in, const int* in_sizes, int n_in,
                              void* d_out, int out_size, void* d_ws, size_t ws_size,
                              hipStream_t stream) {
    const float* x     = (const float*)d_in[0];
    const float* verts = (const float*)d_in[1];
    const int*   edges = (const int*)d_in[2];
    const float* bw    = (const float*)d_in[3];
    const float* bb    = (const float*)d_in[4];
    const float* w0    = (const float*)d_in[5];
    const float* b0    = (const float*)d_in[6];
    const float* w1    = (const float*)d_in[7];
    const float* b1    = (const float*)d_in[8];
    const float* ow    = (const float*)d_in[9];
    const float* ob    = (const float*)d_in[10];
    float* out = (float*)d_out;

    char* w = (char*)d_ws;
    float* P              = (float*)w;          w += (size_t)NPIX * HID * 4;
    unsigned short* feats = (unsigned short*)w; w += (size_t)NV * KB * 2;
    unsigned short* zbf   = (unsigned short*)w; w += (size_t)NV * HID * 2;
    unsigned short* ybf   = (unsigned short*)w; w += (size_t)NV * HID * 2;
    unsigned short* Wt    = (unsigned short*)w; w += (size_t)6 * 128 * KB * 2;
    int* adj              = (int*)w;            w += (size_t)2 * NE * 4;
    unsigned int* items   = (unsigned int*)w;   w += (size_t)2 * NE * 4;
    int* rowstart         = (int*)w;            w += (size_t)(NV + 1) * 4;
    int* gcount           = (int*)w;            w += 512 * 4;
    int* bbase            = (int*)w;            w += 512 * 4;
    int* bcur             = (int*)w;            w += 512 * 4;
    float* acc            = out + (size_t)3 * NV;   // final vert_feats_nopos (fp32)

    // ---- CSR build: histogram -> scan -> bucket sort -> per-bucket place ----
    hipMemsetAsync(gcount, 0, NBKT * 4, stream);
    k_hist<<<NE / 2048, 256, 0, stream>>>((const int4*)edges, gcount);
    k_scan256<<<1, 256, 0, stream>>>(gcount, bbase, bcur, rowstart);
    k_binA<<<NE / 2048, 256, 0, stream>>>((const int4*)edges, bcur, items);
    k_binB<<<NBKT, 256, 0, stream>>>(items, bbase, rowstart, adj);

    k_prepw<<<3, 256, 0, stream>>>(w0, w1, Wt);
    k_project<<<NPIX / 8, 256, 0, stream>>>(x, bw, P);
    k_sample<<<NV / 2, 256, 0, stream>>>(P, verts, bb, feats);

    for (int i = 0; i < 3; ++i) {
        const unsigned short* Wt0 = Wt + (size_t)(2 * i + 0) * 128 * KB;
        const unsigned short* Wt1 = Wt + (size_t)(2 * i + 1) * 128 * KB;
        k_gemm2<<<NV / 256, 256, 0, stream>>>(feats, Wt0, Wt1,
                                              b0 + (size_t)i * HID, b1 + (size_t)i * HID,
                                              ybf, zbf);
        if (i < 2) k_gather<false><<<NV / 16, 256, 0, stream>>>(rowstart, adj, zbf, ybf,
                                                                feats, nullptr, verts,
                                                                nullptr, nullptr, nullptr);
        else       k_gather<true ><<<NV / 16, 256, 0, stream>>>(rowstart, adj, zbf, ybf,
                                                                nullptr, acc, verts,
                                                                ow, ob, out);
    }
}

// Round 6
// 754.140 us; speedup vs baseline: 13.3387x; 1.0671x over previous
//
#include <hip/hip_runtime.h>
#include <cmath>

#define NV   262144
#define NE   786432
#define CIMG 256
#define HID  128
#define NPIX 4096
#define DIN  131
#define KB   160    // bf16 feats padded K (131 -> 160, zeros)
#define KBP  168    // LDS row stride (bank-conflict pad)
#define NBKT 256    // coarse buckets for CSR build (1024 vertices each)

typedef short bf8v __attribute__((ext_vector_type(8)));
typedef float f4v  __attribute__((ext_vector_type(4)));
typedef unsigned short u16x8 __attribute__((ext_vector_type(8)));

__device__ __forceinline__ unsigned short f2bf(float v) {
    unsigned int u = __float_as_uint(v);
    u = u + 0x7fffu + ((u >> 16) & 1u);   // RNE
    return (unsigned short)(u >> 16);
}
__device__ __forceinline__ float bf2f(unsigned short b) {
    return __uint_as_float(((unsigned int)b) << 16);
}

// P[p][j] = sum_c img[c][p] * bw[c][j]; 8 pixels/block, 512 blocks.
__global__ __launch_bounds__(256) void k_project(const float* __restrict__ img,
                                                 const float* __restrict__ bw,
                                                 float* __restrict__ P) {
    int j  = threadIdx.x & 127;
    int pr = threadIdx.x >> 7;
    int pbase = blockIdx.x * 8 + pr * 4;
    float4 a = {0.f, 0.f, 0.f, 0.f};
#pragma unroll 4
    for (int c = 0; c < CIMG; ++c) {
        float bwv = bw[c * HID + j];
        float4 iv = *(const float4*)(img + (size_t)c * NPIX + pbase);
        a.x += iv.x * bwv; a.y += iv.y * bwv;
        a.z += iv.z * bwv; a.w += iv.w * bwv;
    }
    P[(size_t)(pbase + 0) * HID + j] = a.x;
    P[(size_t)(pbase + 1) * HID + j] = a.y;
    P[(size_t)(pbase + 2) * HID + j] = a.z;
    P[(size_t)(pbase + 3) * HID + j] = a.w;
}

// feats[v][0..127] = relu(bilerp + bb) bf16; [128..130]=verts; [131..159]=0
__global__ __launch_bounds__(256) void k_sample(const float* __restrict__ P,
                                                const float* __restrict__ verts,
                                                const float* __restrict__ bb,
                                                unsigned short* __restrict__ feats) {
    int c = threadIdx.x & (HID - 1);
    int v = blockIdx.x * 2 + (threadIdx.x >> 7);
    float vx = verts[(size_t)v * 3 + 0];
    float vy = verts[(size_t)v * 3 + 1];
    float px = (vx + 1.f) * 31.5f;
    float py = (vy + 1.f) * 31.5f;
    float x0f = floorf(px), y0f = floorf(py);
    float wx = px - x0f,   wy = py - y0f;
    int x0 = (int)x0f, y0 = (int)y0f;
    int x0i = min(max(x0, 0), 63);
    int x1i = min(x0i + 1, 63);
    int y0i = min(max(y0, 0), 63);
    int y1i = min(y0i + 1, 63);
    const float* p00 = P + (size_t)(y0i * 64 + x0i) * HID;
    const float* p01 = P + (size_t)(y0i * 64 + x1i) * HID;
    const float* p10 = P + (size_t)(y1i * 64 + x0i) * HID;
    const float* p11 = P + (size_t)(y1i * 64 + x1i) * HID;
    float v00 = p00[c], v01 = p01[c], v10 = p10[c], v11 = p11[c];
    float top = v00 * (1.f - wx) + v01 * wx;
    float bot = v10 * (1.f - wx) + v11 * wx;
    float h = fmaxf(top * (1.f - wy) + bot * wy + bb[c], 0.f);
    unsigned short* fr = feats + (size_t)v * KB;
    fr[c] = f2bf(h);
    if (c < 32) {
        float val = (c < 3) ? verts[(size_t)v * 3 + c] : 0.f;
        fr[128 + c] = f2bf(val);
    }
}

// Wt[m][n][k] bf16, m = layer*2+g, transposed from W[k][n], zero-padded k>=131
__global__ __launch_bounds__(256) void k_prepw(const float* __restrict__ w0,
                                               const float* __restrict__ w1,
                                               unsigned short* __restrict__ Wt) {
    int idx = blockIdx.x * 256 + threadIdx.x;
    if (idx >= 6 * 128) return;
    int m = idx >> 7;
    int n = idx & 127;
    int layer = m >> 1, g = m & 1;
    const float* W = (g ? w1 : w0) + (size_t)layer * DIN * HID;
    unsigned short* dst = Wt + (size_t)(m * 128 + n) * KB;
    for (int k = 0; k < KB; ++k) {
        float v = (k < DIN) ? W[(size_t)k * HID + n] : 0.f;
        dst[k] = f2bf(v);
    }
}

// Fused MFMA GEMM: y = feats@W0+b0 (bf16), z = feats@W1+b1 (bf16).
// A staged in LDS once per block (waves split columns); reg-prefetch next chunk.
__global__ __launch_bounds__(256, 2) void k_gemm2(const unsigned short* __restrict__ feats,
                                                  const unsigned short* __restrict__ Wt0,
                                                  const unsigned short* __restrict__ Wt1,
                                                  const float* __restrict__ bias0,
                                                  const float* __restrict__ bias1,
                                                  unsigned short* __restrict__ y,
                                                  unsigned short* __restrict__ z) {
    __shared__ unsigned short As[64 * KBP];     // 21 KB
    int lane = threadIdx.x & 63;
    int wave = threadIdx.x >> 6;     // column quarter: cols 32*wave..+31
    int l15  = lane & 15;
    int quad = lane >> 4;

    bf8v bfrag[2][2][5];
#pragma unroll
    for (int g = 0; g < 2; ++g) {
        const unsigned short* Wg = g ? Wt1 : Wt0;
#pragma unroll
        for (int ct = 0; ct < 2; ++ct) {
            int n = wave * 32 + ct * 16 + l15;
#pragma unroll
            for (int ks = 0; ks < 5; ++ks)
                bfrag[g][ct][ks] = *(const bf8v*)(Wg + (size_t)n * KB + ks * 32 + quad * 8);
        }
    }
    float bv[2][2];
#pragma unroll
    for (int g = 0; g < 2; ++g)
#pragma unroll
        for (int ct = 0; ct < 2; ++ct)
            bv[g][ct] = (g ? bias1 : bias0)[wave * 32 + ct * 16 + l15];

    int vb0 = blockIdx.x * 256;

    // staging coords: 64 rows x 20 groups of 8 elems; 1280 groups / 256 thr = 5 each
    int srow[5], scol[5];
#pragma unroll
    for (int j = 0; j < 5; ++j) {
        int g = threadIdx.x + 256 * j;
        srow[j] = g / 20;
        scol[j] = (g % 20) * 8;
    }

    u16x8 st[5];
#pragma unroll
    for (int j = 0; j < 5; ++j)
        st[j] = *(const u16x8*)(feats + (size_t)(vb0 + srow[j]) * KB + scol[j]);
#pragma unroll
    for (int j = 0; j < 5; ++j)
        *(u16x8*)(&As[srow[j] * KBP + scol[j]]) = st[j];
    __syncthreads();

    for (int ch = 0; ch < 4; ++ch) {
        if (ch < 3) {
#pragma unroll
            for (int j = 0; j < 5; ++j)
                st[j] = *(const u16x8*)(feats + (size_t)(vb0 + (ch + 1) * 64 + srow[j]) * KB + scol[j]);
        }
        f4v acc[4][2][2];
#pragma unroll
        for (int m = 0; m < 4; ++m)
#pragma unroll
            for (int g = 0; g < 2; ++g)
#pragma unroll
                for (int ct = 0; ct < 2; ++ct) {
                    f4v t = {bv[g][ct], bv[g][ct], bv[g][ct], bv[g][ct]};
                    acc[m][g][ct] = t;
                }
#pragma unroll
        for (int ks = 0; ks < 5; ++ks) {
            bf8v af[4];
#pragma unroll
            for (int m = 0; m < 4; ++m)
                af[m] = *(const bf8v*)(&As[(m * 16 + l15) * KBP + ks * 32 + quad * 8]);
#pragma unroll
            for (int m = 0; m < 4; ++m)
#pragma unroll
                for (int g = 0; g < 2; ++g)
#pragma unroll
                    for (int ct = 0; ct < 2; ++ct)
                        acc[m][g][ct] = __builtin_amdgcn_mfma_f32_16x16x32_bf16(
                            af[m], bfrag[g][ct][ks], acc[m][g][ct], 0, 0, 0);
        }
        int vbase = vb0 + ch * 64;
#pragma unroll
        for (int g = 0; g < 2; ++g) {
            unsigned short* dst = g ? z : y;
#pragma unroll
            for (int m = 0; m < 4; ++m)
#pragma unroll
                for (int ct = 0; ct < 2; ++ct) {
                    int c = wave * 32 + ct * 16 + l15;
#pragma unroll
                    for (int r = 0; r < 4; ++r) {
                        int v = vbase + m * 16 + quad * 4 + r;
                        dst[(size_t)v * HID + c] = f2bf(acc[m][g][ct][r]);
                    }
                }
        }
        __syncthreads();
        if (ch < 3) {
#pragma unroll
            for (int j = 0; j < 5; ++j)
                *(u16x8*)(&As[srow[j] * KBP + scol[j]]) = st[j];
            __syncthreads();
        }
    }
}

// ---- CSR build via 2-level bucket sort ----
__global__ __launch_bounds__(256) void k_hist(const int4* __restrict__ edges4,
                                              int* __restrict__ gcount) {
    __shared__ int hist[NBKT];
    if (threadIdx.x < NBKT) hist[threadIdx.x] = 0;
    __syncthreads();
#pragma unroll
    for (int i = 0; i < 4; ++i) {
        int4 e = edges4[(size_t)blockIdx.x * 1024 + i * 256 + threadIdx.x];
        atomicAdd(&hist[e.x >> 10], 1);
        atomicAdd(&hist[e.y >> 10], 1);
        atomicAdd(&hist[e.z >> 10], 1);
        atomicAdd(&hist[e.w >> 10], 1);
    }
    __syncthreads();
    if (threadIdx.x < NBKT) atomicAdd(&gcount[threadIdx.x], hist[threadIdx.x]);
}

__global__ __launch_bounds__(256) void k_scan256(const int* __restrict__ gcount,
                                                 int* __restrict__ bbase,
                                                 int* __restrict__ bcur,
                                                 int* __restrict__ rowstart) {
    __shared__ int s[NBKT];
    int t = threadIdx.x;
    int c = gcount[t];
    s[t] = c;
    __syncthreads();
    for (int off = 1; off < NBKT; off <<= 1) {
        int v = (t >= off) ? s[t - off] : 0;
        __syncthreads();
        s[t] += v;
        __syncthreads();
    }
    bbase[t] = s[t] - c;
    bcur[t]  = s[t] - c;
    if (t == NBKT - 1) {
        bbase[NBKT] = s[t];
        rowstart[NV] = s[t];
    }
}

__global__ __launch_bounds__(256) void k_binA(const int4* __restrict__ edges4,
                                              int* __restrict__ bcur,
                                              unsigned int* __restrict__ items) {
    __shared__ int hist[NBKT];
    __shared__ int loff[NBKT];
    __shared__ int gbase[NBKT];
    __shared__ int sscan[256];
    __shared__ unsigned int staged[4096];
    __shared__ unsigned char staged_b[4096];

    if (threadIdx.x < NBKT) hist[threadIdx.x] = 0;
    __syncthreads();

    int vv[16], uu[16], rk[16];
#pragma unroll
    for (int i = 0; i < 4; ++i) {
        int4 e = edges4[(size_t)blockIdx.x * 1024 + i * 256 + threadIdx.x];
        vv[4*i+0] = e.x; uu[4*i+0] = e.y;
        vv[4*i+1] = e.y; uu[4*i+1] = e.x;
        vv[4*i+2] = e.z; uu[4*i+2] = e.w;
        vv[4*i+3] = e.w; uu[4*i+3] = e.z;
    }
#pragma unroll
    for (int i = 0; i < 16; ++i) rk[i] = atomicAdd(&hist[vv[i] >> 10], 1);
    __syncthreads();
    {
        int t = threadIdx.x;
        int c = hist[t];
        sscan[t] = c;
        __syncthreads();
        for (int off = 1; off < 256; off <<= 1) {
            int x = (t >= off) ? sscan[t - off] : 0;
            __syncthreads();
            sscan[t] += x;
            __syncthreads();
        }
        loff[t] = sscan[t] - c;
    }
    __syncthreads();
#pragma unroll
    for (int i = 0; i < 16; ++i) {
        int b = vv[i] >> 10;
        int pos = loff[b] + rk[i];
        staged[pos] = ((unsigned int)(vv[i] & 1023) << 18) | (unsigned int)uu[i];
        staged_b[pos] = (unsigned char)b;
    }
    __syncthreads();
    if (threadIdx.x < NBKT)
        gbase[threadIdx.x] = atomicAdd(&bcur[threadIdx.x], hist[threadIdx.x]);
    __syncthreads();
#pragma unroll
    for (int i = 0; i < 16; ++i) {
        int s = i * 256 + threadIdx.x;
        int b = staged_b[s];
        items[(size_t)gbase[b] + (s - loff[b])] = staged[s];
    }
}

__global__ __launch_bounds__(256) void k_binB(const unsigned int* __restrict__ items,
                                              const int* __restrict__ bbase,
                                              int* __restrict__ rowstart,
                                              int* __restrict__ adj) {
    __shared__ int cnt[1024];
    __shared__ int sscan[256];
    int b = blockIdx.x;
    int base = bbase[b];
    int size = bbase[b + 1] - base;
#pragma unroll
    for (int i = 0; i < 4; ++i) cnt[i * 256 + threadIdx.x] = 0;
    __syncthreads();
    for (int i = threadIdx.x; i < size; i += 256) {
        unsigned int it = items[(size_t)base + i];
        atomicAdd(&cnt[(it >> 18) & 1023], 1);
    }
    __syncthreads();
    {
        int j = threadIdx.x;
        int c[4], t = 0;
#pragma unroll
        for (int i = 0; i < 4; ++i) { c[i] = cnt[4 * j + i]; t += c[i]; }
        sscan[j] = t;
        __syncthreads();
        for (int off = 1; off < 256; off <<= 1) {
            int x = (j >= off) ? sscan[j - off] : 0;
            __syncthreads();
            sscan[j] += x;
            __syncthreads();
        }
        int pre = sscan[j] - t;
#pragma unroll
        for (int i = 0; i < 4; ++i) {
            cnt[4 * j + i] = pre;
            rowstart[b * 1024 + 4 * j + i] = base + pre;
            pre += c[i];
        }
    }
    __syncthreads();
    for (int i = threadIdx.x; i < size; i += 256) {
        unsigned int it = items[(size_t)base + i];
        int lv = (it >> 18) & 1023;
        int rel = atomicAdd(&cnt[lv], 1);
        adj[base + rel] = (int)(it & 0x3FFFFu);
    }
}

// relu(y[v] + sum_{u in N(v)} z[u]); 16 lanes/vertex, unroll-2 for MLP.
template <bool LAST>
__global__ __launch_bounds__(256) void k_gather(const int* __restrict__ rowstart,
                                                const int* __restrict__ adj,
                                                const unsigned short* __restrict__ zbf,
                                                const unsigned short* __restrict__ ybf,
                                                unsigned short* __restrict__ featdst,
                                                float* __restrict__ accdst,
                                                const float* __restrict__ verts,
                                                const float* __restrict__ ow,
                                                const float* __restrict__ ob,
                                                float* __restrict__ outp) {
    __shared__ float owl[DIN * 3];
    if (LAST) {
        for (int idx = threadIdx.x; idx < DIN * 3; idx += 256) owl[idx] = ow[idx];
        __syncthreads();
    }
    int cq = threadIdx.x & 15;
    int v  = blockIdx.x * 16 + (threadIdx.x >> 4);
    int start = rowstart[v], end = rowstart[v + 1];
    u16x8 yy = *(const u16x8*)(ybf + (size_t)v * HID + 8 * cq);
    float a[8];
#pragma unroll
    for (int i = 0; i < 8; ++i) a[i] = bf2f(yy[i]);
    int n = start;
    for (; n + 2 <= end; n += 2) {
        int u0 = adj[n], u1 = adj[n + 1];
        u16x8 z0 = *(const u16x8*)(zbf + (size_t)u0 * HID + 8 * cq);
        u16x8 z1 = *(const u16x8*)(zbf + (size_t)u1 * HID + 8 * cq);
#pragma unroll
        for (int i = 0; i < 8; ++i) a[i] += bf2f(z0[i]) + bf2f(z1[i]);
    }
    if (n < end) {
        int u = adj[n];
        u16x8 zz = *(const u16x8*)(zbf + (size_t)u * HID + 8 * cq);
#pragma unroll
        for (int i = 0; i < 8; ++i) a[i] += bf2f(zz[i]);
    }
#pragma unroll
    for (int i = 0; i < 8; ++i) a[i] = fmaxf(a[i], 0.f);
    if (LAST) {
        float4 lo = {a[0], a[1], a[2], a[3]};
        float4 hi = {a[4], a[5], a[6], a[7]};
        float* dst = accdst + (size_t)v * HID + 8 * cq;
        *(float4*)(dst + 0) = lo;
        *(float4*)(dst + 4) = hi;
        float d0 = 0.f, d1 = 0.f, d2 = 0.f;
#pragma unroll
        for (int i = 0; i < 8; ++i) {
            int k = 8 * cq + i;
            d0 += a[i] * owl[k * 3 + 0];
            d1 += a[i] * owl[k * 3 + 1];
            d2 += a[i] * owl[k * 3 + 2];
        }
#pragma unroll
        for (int off = 8; off > 0; off >>= 1) {
            d0 += __shfl_down(d0, off, 16);
            d1 += __shfl_down(d1, off, 16);
            d2 += __shfl_down(d2, off, 16);
        }
        if (cq == 0) {
            float vx = verts[(size_t)v * 3 + 0];
            float vy = verts[(size_t)v * 3 + 1];
            float vz = verts[(size_t)v * 3 + 2];
            d0 += vx * owl[128*3+0] + vy * owl[129*3+0] + vz * owl[130*3+0] + ob[0];
            d1 += vx * owl[128*3+1] + vy * owl[129*3+1] + vz * owl[130*3+1] + ob[1];
            d2 += vx * owl[128*3+2] + vy * owl[129*3+2] + vz * owl[130*3+2] + ob[2];
            outp[(size_t)v * 3 + 0] = vx + tanhf(d0);
            outp[(size_t)v * 3 + 1] = vy + tanhf(d1);
            outp[(size_t)v * 3 + 2] = vz + tanhf(d2);
        }
    } else {
        u16x8 o;
#pragma unroll
        for (int i = 0; i < 8; ++i) o[i] = f2bf(a[i]);
        *(u16x8*)(featdst + (size_t)v * KB + 8 * cq) = o;
    }
}

extern "C" void kernel_launch(void* const* d_in, const int* in_sizes, int n_in,
                              void* d_out, int out_size, void* d_ws, size_t ws_size,
                              hipStream_t stream) {
    const float* x     = (const float*)d_in[0];
    const float* verts = (const float*)d_in[1];
    const int*   edges = (const int*)d_in[2];
    const float* bw    = (const float*)d_in[3];
    const float* bb    = (const float*)d_in[4];
    const float* w0    = (const float*)d_in[5];
    const float* b0    = (const float*)d_in[6];
    const float* w1    = (const float*)d_in[7];
    const float* b1    = (const float*)d_in[8];
    const float* ow    = (const float*)d_in[9];
    const float* ob    = (const float*)d_in[10];
    float* out = (float*)d_out;

    char* w = (char*)d_ws;
    float* P              = (float*)w;          w += (size_t)NPIX * HID * 4;
    unsigned short* feats = (unsigned short*)w; w += (size_t)NV * KB * 2;
    unsigned short* zbf   = (unsigned short*)w; w += (size_t)NV * HID * 2;
    unsigned short* ybf   = (unsigned short*)w; w += (size_t)NV * HID * 2;
    unsigned short* Wt    = (unsigned short*)w; w += (size_t)6 * 128 * KB * 2;
    int* adj              = (int*)w;            w += (size_t)2 * NE * 4;
    unsigned int* items   = (unsigned int*)w;   w += (size_t)2 * NE * 4;
    int* rowstart         = (int*)w;            w += (size_t)(NV + 1) * 4;
    int* gcount           = (int*)w;            w += 512 * 4;
    int* bbase            = (int*)w;            w += 512 * 4;
    int* bcur             = (int*)w;            w += 512 * 4;
    float* acc            = out + (size_t)3 * NV;

    hipMemsetAsync(gcount, 0, NBKT * 4, stream);
    k_hist<<<NE / 2048, 256, 0, stream>>>((const int4*)edges, gcount);
    k_scan256<<<1, 256, 0, stream>>>(gcount, bbase, bcur, rowstart);
    k_binA<<<NE / 2048, 256, 0, stream>>>((const int4*)edges, bcur, items);
    k_binB<<<NBKT, 256, 0, stream>>>(items, bbase, rowstart, adj);

    k_prepw<<<3, 256, 0, stream>>>(w0, w1, Wt);
    k_project<<<NPIX / 8, 256, 0, stream>>>(x, bw, P);
    k_sample<<<NV / 2, 256, 0, stream>>>(P, verts, bb, feats);

    for (int i = 0; i < 3; ++i) {
        const unsigned short* Wt0 = Wt + (size_t)(2 * i + 0) * 128 * KB;
        const unsigned short* Wt1 = Wt + (size_t)(2 * i + 1) * 128 * KB;
        k_gemm2<<<NV / 256, 256, 0, stream>>>(feats, Wt0, Wt1,
                                              b0 + (size_t)i * HID, b1 + (size_t)i * HID,
                                              ybf, zbf);
        if (i < 2) k_gather<false><<<NV / 16, 256, 0, stream>>>(rowstart, adj, zbf, ybf,
                                                                feats, nullptr, verts,
                                                                nullptr, nullptr, nullptr);
        else       k_gather<true ><<<NV / 16, 256, 0, stream>>>(rowstart, adj, zbf, ybf,
                                                                nullptr, acc, verts,
                                                                ow, ob, out);
    }
}